// Round 1
// baseline (6032.047 us; speedup 1.0000x reference)
//
#include <hip/hip_runtime.h>

#define Bd 4
#define Td 1024
#define Ld 1024
#define HIDd 1024
#define BBd 512
#define FFd 4096
#define Hd 8
#define ROWSd 4096   // B*T = B*L

__device__ __forceinline__ float gelu_f(float x) {
    return 0.5f * x * (1.f + tanhf(0.7978845608028654f * (x + 0.044715f * x * x * x)));
}

// ---------------- LayerNorm: one block per row ----------------
template<int D>
__global__ __launch_bounds__(256) void ln_kernel(const float* __restrict__ x,
                                                 const float* __restrict__ g,
                                                 const float* __restrict__ b,
                                                 float* __restrict__ y)
{
    const int row = blockIdx.x;
    const int tid = threadIdx.x;
    const float* xr = x + (size_t)row * D;
    float* yr = y + (size_t)row * D;
    constexpr int PT = D / 256;
    float vals[PT];
    float s = 0.f, ss = 0.f;
#pragma unroll
    for (int i = 0; i < PT; i++) {
        float v = xr[tid + i * 256];
        vals[i] = v; s += v; ss += v * v;
    }
#pragma unroll
    for (int o = 32; o > 0; o >>= 1) { s += __shfl_down(s, o); ss += __shfl_down(ss, o); }
    __shared__ float rs[4], rss[4];
    const int wid = tid >> 6, lane = tid & 63;
    if (lane == 0) { rs[wid] = s; rss[wid] = ss; }
    __syncthreads();
    if (tid == 0) {
        float a = 0.f, c = 0.f;
        for (int i = 0; i < 4; i++) { a += rs[i]; c += rss[i]; }
        rs[0] = a; rss[0] = c;
    }
    __syncthreads();
    const float mean = rs[0] / D;
    const float var  = rss[0] / D - mean * mean;
    const float inv  = rsqrtf(fmaxf(var, 0.f) + 1e-6f);
#pragma unroll
    for (int i = 0; i < PT; i++) {
        const int idx = tid + i * 256;
        yr[idx] = (vals[i] - mean) * inv * g[idx] + b[idx];
    }
}

// ---------------- fp32 tiled GEMM: C[M,N] = A[M,K] @ W[K,N] + bias (+res) (gelu?) ----
// 256 threads, 64x64 tile, BK=16, 4x4 microtile per thread.
template<int ACT, bool HAS_RES>
__global__ __launch_bounds__(256) void gemm_kernel(const float* __restrict__ A,
                                                   const float* __restrict__ W,
                                                   const float* __restrict__ bias,
                                                   const float* __restrict__ res,
                                                   float* __restrict__ C,
                                                   int M, int N, int K)
{
    __shared__ float As[16][65];   // [k][m], padded: write stride 65 -> conflict-free
    __shared__ float Ws[16][64];   // [k][n]
    const int tid = threadIdx.x;
    const int tx = tid & 15, ty = tid >> 4;
    const int n0 = blockIdx.x * 64, m0 = blockIdx.y * 64;
    float acc[4][4] = {};
    for (int k0 = 0; k0 < K; k0 += 16) {
#pragma unroll
        for (int i = 0; i < 4; i++) {
            const int r = (tid >> 4) + i * 16;   // 0..63 (m)
            const int c = tid & 15;              // 0..15 (k)
            As[c][r] = A[(size_t)(m0 + r) * K + k0 + c];
        }
#pragma unroll
        for (int i = 0; i < 4; i++) {
            const int r = (tid >> 6) + i * 4;    // 0..15 (k)
            const int c = tid & 63;              // 0..63 (n)
            Ws[r][c] = W[(size_t)(k0 + r) * N + n0 + c];
        }
        __syncthreads();
#pragma unroll
        for (int kk = 0; kk < 16; kk++) {
            float a[4], w[4];
#pragma unroll
            for (int i = 0; i < 4; i++) a[i] = As[kk][ty * 4 + i];
#pragma unroll
            for (int j = 0; j < 4; j++) w[j] = Ws[kk][tx * 4 + j];
#pragma unroll
            for (int i = 0; i < 4; i++)
#pragma unroll
                for (int j = 0; j < 4; j++)
                    acc[i][j] += a[i] * w[j];
        }
        __syncthreads();
    }
#pragma unroll
    for (int i = 0; i < 4; i++) {
#pragma unroll
        for (int j = 0; j < 4; j++) {
            const int m = m0 + ty * 4 + i, n = n0 + tx * 4 + j;
            float v = acc[i][j] + bias[n];
            if (ACT == 1) v = gelu_f(v);
            if (HAS_RES) v += res[(size_t)m * N + n];
            C[(size_t)m * N + n] = v;
        }
    }
}

// ---------------- gate = sigmoid(qc . gw + gb), one wave per (b,t), loop h -----------
__global__ __launch_bounds__(64) void gate_kernel(const float* __restrict__ qc,
                                                  const float* __restrict__ gw,
                                                  const float* __restrict__ gb,
                                                  float* __restrict__ gate)
{
    const int bt = blockIdx.x;           // b*T + t
    const int d = threadIdx.x;           // 0..63
    const float w = gw[d];
    const int b = bt >> 10, t = bt & 1023;
    const float gbv = gb[0];
#pragma unroll
    for (int h = 0; h < Hd; h++) {
        float v = qc[(size_t)bt * BBd + h * 64 + d] * w;
#pragma unroll
        for (int o = 32; o > 0; o >>= 1) v += __shfl_xor(v, o);
        if (d == 0)
            gate[((size_t)b * Hd + h) * Td + t] = 1.f / (1.f + __expf(-(v + gbv)));
    }
}

// ---------------- fused attention ----------------
// Q/K/V layout [B, T, H*D]; out same. One block = (b,h) x 8 query rows.
// SA variant: scores = (qc.ksum + qp.kc)*scale + gate*sb, causal mask.
template<int D, bool CAUSAL, bool SA>
__global__ __launch_bounds__(256) void attn_kernel(const float* __restrict__ Q,
                                                   const float* __restrict__ Qp,
                                                   const float* __restrict__ Km,
                                                   const float* __restrict__ Kc,
                                                   const float* __restrict__ V,
                                                   const float* __restrict__ gate,
                                                   const float* __restrict__ sb,
                                                   float* __restrict__ O,
                                                   int Tq, int Tk, float scale)
{
    constexpr int QR = 8, KT = 64;
    const int bh = blockIdx.y;               // b*H + h
    const int b = bh >> 3, h = bh & 7;
    const int q0 = blockIdx.x * QR;
    const int tid = threadIdx.x;
    const int NH = Hd * D;

    __shared__ float Qs[QR][D];
    __shared__ float Qps[SA ? QR : 1][SA ? D : 1];
    __shared__ float Kt[KT][D + 1];
    __shared__ float Kct[SA ? KT : 1][SA ? (D + 1) : 1];
    __shared__ float S[QR][1024];
    __shared__ float rsum[QR];

    const size_t qbase = ((size_t)b * Tq) * NH + (size_t)h * D;
    const size_t kbase = ((size_t)b * Tk) * NH + (size_t)h * D;

    for (int idx = tid; idx < QR * D; idx += 256) {
        const int r = idx / D, d = idx % D;
        Qs[r][d] = Q[qbase + (size_t)(q0 + r) * NH + d];
        if constexpr (SA) Qps[r][d] = Qp[qbase + (size_t)(q0 + r) * NH + d];
    }

    // ---- scores ----
    for (int k0 = 0; k0 < Tk; k0 += KT) {
        __syncthreads();
        for (int idx = tid; idx < KT * D; idx += 256) {
            const int r = idx / D, d = idx % D;
            Kt[r][d] = Km[kbase + (size_t)(k0 + r) * NH + d];
            if constexpr (SA) Kct[r][d] = Kc[kbase + (size_t)(k0 + r) * NH + d];
        }
        __syncthreads();
#pragma unroll
        for (int pp = 0; pp < 2; pp++) {
            const int p = tid + pp * 256;      // 0..511
            const int r = p >> 6, kk = p & 63;
            const int q = q0 + r, k = k0 + kk;
            float s = 0.f;
#pragma unroll 8
            for (int d = 0; d < D; d++) s += Qs[r][d] * Kt[kk][d];
            if constexpr (SA) {
                float s2 = 0.f;
#pragma unroll 8
                for (int d = 0; d < D; d++) s2 += Qps[r][d] * Kct[kk][d];
                s = (s + s2) * scale
                    + gate[(size_t)bh * Tq + q] * sb[((size_t)bh * Tq + q) * Tk + k];
            } else {
                s *= scale;
            }
            if (CAUSAL && k > q) s = -INFINITY;
            S[r][k] = s;
        }
    }
    __syncthreads();

    // ---- softmax per row (one wave per row, 2 rows per wave) ----
    {
        const int wid = tid >> 6, lane = tid & 63;
        for (int r = wid; r < QR; r += 4) {
            float mx = -INFINITY;
            for (int k = lane; k < Tk; k += 64) mx = fmaxf(mx, S[r][k]);
#pragma unroll
            for (int o = 32; o > 0; o >>= 1) mx = fmaxf(mx, __shfl_xor(mx, o));
            float sum = 0.f;
            for (int k = lane; k < Tk; k += 64) {
                const float e = __expf(S[r][k] - mx);
                S[r][k] = e; sum += e;
            }
#pragma unroll
            for (int o = 32; o > 0; o >>= 1) sum += __shfl_xor(sum, o);
            if (lane == 0) rsum[r] = sum;
        }
    }
    __syncthreads();

    // ---- PV ----
    constexpr int IT = QR * D / 256;
    float acc[IT] = {};
    for (int k0 = 0; k0 < Tk; k0 += KT) {
        __syncthreads();
        for (int idx = tid; idx < KT * D; idx += 256) {
            const int r = idx / D, d = idx % D;
            Kt[r][d] = V[kbase + (size_t)(k0 + r) * NH + d];
        }
        __syncthreads();
#pragma unroll
        for (int i = 0; i < IT; i++) {
            const int idx = tid + i * 256;
            const int r = idx / D, d = idx % D;
            float a = acc[i];
#pragma unroll 16
            for (int kk = 0; kk < KT; kk++)
                a += S[r][k0 + kk] * Kt[kk][d];
            acc[i] = a;
        }
    }
#pragma unroll
    for (int i = 0; i < IT; i++) {
        const int idx = tid + i * 256;
        const int r = idx / D, d = idx % D;
        O[qbase + (size_t)(q0 + r) * NH + d] = acc[i] / rsum[r];
    }
}

// ---------------------------------------------------------------
extern "C" void kernel_launch(void* const* d_in, const int* in_sizes, int n_in,
                              void* d_out, int out_size, void* d_ws, size_t ws_size,
                              hipStream_t stream)
{
    const float* layout_content = (const float*)d_in[0];
    const float* text_x         = (const float*)d_in[1];
    const float* text_memory    = (const float*)d_in[2];
    const float* spatial_bias   = (const float*)d_in[3];
    const float* layout_pos     = (const float*)d_in[4];
    // d_in[5] trg_mask (tril -> handled analytically), d_in[6] src_mask (all ones -> no-op)
    const float* sa_q_w = (const float*)d_in[7];   const float* sa_q_b = (const float*)d_in[8];
    const float* sa_k_w = (const float*)d_in[9];   const float* sa_k_b = (const float*)d_in[10];
    const float* sa_v_w = (const float*)d_in[11];  const float* sa_v_b = (const float*)d_in[12];
    const float* sa_pk_w = (const float*)d_in[13]; const float* sa_pk_b = (const float*)d_in[14];
    const float* sa_pq_w = (const float*)d_in[15]; const float* sa_pq_b = (const float*)d_in[16];
    const float* sa_o_w = (const float*)d_in[17];  const float* sa_o_b = (const float*)d_in[18];
    const float* lt_q_w = (const float*)d_in[19];  const float* lt_q_b = (const float*)d_in[20];
    const float* lt_k_w = (const float*)d_in[21];  const float* lt_k_b = (const float*)d_in[22];
    const float* lt_v_w = (const float*)d_in[23];  const float* lt_v_b = (const float*)d_in[24];
    const float* lt_o_w = (const float*)d_in[25];  const float* lt_o_b = (const float*)d_in[26];
    const float* tl_q_w = (const float*)d_in[27];  const float* tl_q_b = (const float*)d_in[28];
    const float* tl_k_w = (const float*)d_in[29];  const float* tl_k_b = (const float*)d_in[30];
    const float* tl_v_w = (const float*)d_in[31];  const float* tl_v_b = (const float*)d_in[32];
    const float* tl_o_w = (const float*)d_in[33];  const float* tl_o_b = (const float*)d_in[34];
    const float* ltp_w = (const float*)d_in[35];   const float* ltp_b = (const float*)d_in[36];
    const float* tlp_w = (const float*)d_in[37];   const float* tlp_b = (const float*)d_in[38];
    const float* lf1_w = (const float*)d_in[39];   const float* lf1_b = (const float*)d_in[40];
    const float* lf2_w = (const float*)d_in[41];   const float* lf2_b = (const float*)d_in[42];
    const float* tf1_w = (const float*)d_in[43];   const float* tf1_b = (const float*)d_in[44];
    const float* tf2_w = (const float*)d_in[45];   const float* tf2_b = (const float*)d_in[46];
    const float* sa_g_w = (const float*)d_in[47];  const float* sa_g_b = (const float*)d_in[48];
    const float* ln1_g = (const float*)d_in[49];   const float* ln1_b = (const float*)d_in[50];
    const float* ln2_g = (const float*)d_in[51];   const float* ln2_b = (const float*)d_in[52];
    const float* tn1_g = (const float*)d_in[53];   const float* tn1_b = (const float*)d_in[54];
    const float* lfn_g = (const float*)d_in[55];   const float* lfn_b = (const float*)d_in[56];
    const float* tfn_g = (const float*)d_in[57];   const float* tfn_b = (const float*)d_in[58];

    float* out = (float*)d_out;
    float* layout_out = out;                       // [4,1024,512]
    float* text_out   = out + (size_t)ROWSd * BBd; // [4,1024,1024]

    // workspace layout (floats); peak ~192 MB
    const size_t M4 = (size_t)ROWSd * 1024;  // 4M floats
    const size_t M2 = (size_t)ROWSd * 512;   // 2M floats
    float* ws   = (float*)d_ws;
    float* XN   = ws;            // LN outputs (<=4M)
    float* Qb   = XN + M4;       // q proj (<=4M)
    float* Kb   = Qb + M4;       // k proj (<=4M)
    float* Vb   = Kb + M4;       // v proj (<=4M)
    float* KS   = Vb + M4;       // ksum = kc+kp (2M)
    float* QP   = KS + M2;       // qp (2M)
    float* GATE = QP + M2;       // [B,H,T] 32768
    float* CTX  = GATE + 65536;  // attention ctx (<=4M)
    float* LSO  = CTX + M4;      // layout_self_out (2M)
    float* LPRE = LSO + M2;      // layout_pre (2M)
    float* TPRE = LPRE + M2;     // text_pre (4M)
    float* HB   = TPRE + M4;     // FFN hidden (16M)

    const dim3 blk(256);
    const dim3 gln(ROWSd);
    auto gemm_grid = [](int M, int N) { return dim3(N / 64, M / 64); };

    // ===== layout self-attention =====
    ln_kernel<512><<<gln, blk, 0, stream>>>(layout_content, ln1_g, ln1_b, XN);
    gemm_kernel<0, false><<<gemm_grid(ROWSd, 512), blk, 0, stream>>>(XN, sa_q_w, sa_q_b, nullptr, Qb, ROWSd, 512, 512);
    gemm_kernel<0, false><<<gemm_grid(ROWSd, 512), blk, 0, stream>>>(XN, sa_k_w, sa_k_b, nullptr, Kb, ROWSd, 512, 512);
    gemm_kernel<0, false><<<gemm_grid(ROWSd, 512), blk, 0, stream>>>(XN, sa_v_w, sa_v_b, nullptr, Vb, ROWSd, 512, 512);
    gemm_kernel<0, false><<<gemm_grid(ROWSd, 512), blk, 0, stream>>>(layout_pos, sa_pq_w, sa_pq_b, nullptr, QP, ROWSd, 512, 512);
    gemm_kernel<0, true><<<gemm_grid(ROWSd, 512), blk, 0, stream>>>(layout_pos, sa_pk_w, sa_pk_b, Kb, KS, ROWSd, 512, 512); // ksum = kc + kp
    gate_kernel<<<dim3(ROWSd), dim3(64), 0, stream>>>(Qb, sa_g_w, sa_g_b, GATE);
    attn_kernel<64, true, true><<<dim3(Td / 8, Bd * Hd), blk, 0, stream>>>(
        Qb, QP, KS, Kb, Vb, GATE, spatial_bias, CTX, Td, Td, 0.125f);
    gemm_kernel<0, true><<<gemm_grid(ROWSd, 512), blk, 0, stream>>>(CTX, sa_o_w, sa_o_b, layout_content, LSO, ROWSd, 512, 512);

    // ===== layout -> text cross attention =====
    ln_kernel<512><<<gln, blk, 0, stream>>>(LSO, ln2_g, ln2_b, XN);
    gemm_kernel<0, false><<<gemm_grid(ROWSd, 1024), blk, 0, stream>>>(XN, lt_q_w, lt_q_b, nullptr, Qb, ROWSd, 1024, 512);
    gemm_kernel<0, false><<<gemm_grid(ROWSd, 1024), blk, 0, stream>>>(text_memory, lt_k_w, lt_k_b, nullptr, Kb, ROWSd, 1024, 1024);
    gemm_kernel<0, false><<<gemm_grid(ROWSd, 1024), blk, 0, stream>>>(text_memory, lt_v_w, lt_v_b, nullptr, Vb, ROWSd, 1024, 1024);
    attn_kernel<128, false, false><<<dim3(Td / 8, Bd * Hd), blk, 0, stream>>>(
        Qb, nullptr, Kb, nullptr, Vb, nullptr, nullptr, CTX, Td, Ld, 0.08838834764831845f);
    gemm_kernel<0, false><<<gemm_grid(ROWSd, 1024), blk, 0, stream>>>(CTX, lt_o_w, lt_o_b, nullptr, Qb, ROWSd, 1024, 1024);
    gemm_kernel<0, true><<<gemm_grid(ROWSd, 512), blk, 0, stream>>>(Qb, ltp_w, ltp_b, LSO, LPRE, ROWSd, 512, 1024);

    // ===== layout FFN =====
    ln_kernel<512><<<gln, blk, 0, stream>>>(LPRE, lfn_g, lfn_b, XN);
    gemm_kernel<1, false><<<gemm_grid(ROWSd, 4096), blk, 0, stream>>>(XN, lf1_w, lf1_b, nullptr, HB, ROWSd, 4096, 512);
    gemm_kernel<0, true><<<gemm_grid(ROWSd, 512), blk, 0, stream>>>(HB, lf2_w, lf2_b, LPRE, layout_out, ROWSd, 512, 4096);

    // ===== text -> layout cross attention =====
    ln_kernel<1024><<<gln, blk, 0, stream>>>(text_x, tn1_g, tn1_b, XN);
    gemm_kernel<0, false><<<gemm_grid(ROWSd, 512), blk, 0, stream>>>(XN, tl_q_w, tl_q_b, nullptr, Qb, ROWSd, 512, 1024);
    gemm_kernel<0, false><<<gemm_grid(ROWSd, 512), blk, 0, stream>>>(layout_out, tl_k_w, tl_k_b, nullptr, Kb, ROWSd, 512, 512);
    gemm_kernel<0, false><<<gemm_grid(ROWSd, 512), blk, 0, stream>>>(layout_out, tl_v_w, tl_v_b, nullptr, Vb, ROWSd, 512, 512);
    attn_kernel<64, false, false><<<dim3(Td / 8, Bd * Hd), blk, 0, stream>>>(
        Qb, nullptr, Kb, nullptr, Vb, nullptr, nullptr, CTX, Td, Td, 0.125f);
    gemm_kernel<0, false><<<gemm_grid(ROWSd, 512), blk, 0, stream>>>(CTX, tl_o_w, tl_o_b, nullptr, Qb, ROWSd, 512, 512);
    gemm_kernel<0, true><<<gemm_grid(ROWSd, 1024), blk, 0, stream>>>(Qb, tlp_w, tlp_b, text_x, TPRE, ROWSd, 1024, 512);

    // ===== text FFN =====
    ln_kernel<1024><<<gln, blk, 0, stream>>>(TPRE, tfn_g, tfn_b, XN);
    gemm_kernel<1, false><<<gemm_grid(ROWSd, 4096), blk, 0, stream>>>(XN, tf1_w, tf1_b, nullptr, HB, ROWSd, 4096, 1024);
    gemm_kernel<0, true><<<gemm_grid(ROWSd, 1024), blk, 0, stream>>>(HB, tf2_w, tf2_b, TPRE, text_out, ROWSd, 1024, 4096);
}

// Round 2
// 2854.099 us; speedup vs baseline: 2.1135x; 2.1135x over previous
//
#include <hip/hip_runtime.h>

#define Bd 4
#define Td 1024
#define Ld 1024
#define HIDd 1024
#define BBd 512
#define FFd 4096
#define Hd 8
#define ROWSd 4096   // B*T = B*L

typedef unsigned short ushort_t;
typedef __attribute__((ext_vector_type(8))) short bf16x8;
typedef __attribute__((ext_vector_type(4))) float f32x4;

__device__ __forceinline__ float gelu_f(float x) {
    return 0.5f * x * (1.f + tanhf(0.7978845608028654f * (x + 0.044715f * x * x * x)));
}

__device__ __forceinline__ ushort_t f2b(float x) {
    union { float f; unsigned u; } v; v.f = x;
    unsigned r = v.u + 0x7fffu + ((v.u >> 16) & 1u);   // round-to-nearest-even
    return (ushort_t)(r >> 16);
}

__device__ __forceinline__ void gload_lds16(const ushort_t* g, ushort_t* l) {
    __builtin_amdgcn_global_load_lds((__attribute__((address_space(1))) void*)(void*)g,
                                     (__attribute__((address_space(3))) void*)l,
                                     16, 0, 0);
}

// ---------------- LayerNorm: one block per row, bf16 out ----------------
template<int D>
__global__ __launch_bounds__(256) void ln_kernel(const float* __restrict__ x,
                                                 const float* __restrict__ g,
                                                 const float* __restrict__ b,
                                                 ushort_t* __restrict__ y)
{
    const int row = blockIdx.x;
    const int tid = threadIdx.x;
    const float* xr = x + (size_t)row * D;
    ushort_t* yr = y + (size_t)row * D;
    constexpr int PT = D / 256;
    float vals[PT];
    float s = 0.f, ss = 0.f;
#pragma unroll
    for (int i = 0; i < PT; i++) {
        float v = xr[tid + i * 256];
        vals[i] = v; s += v; ss += v * v;
    }
#pragma unroll
    for (int o = 32; o > 0; o >>= 1) { s += __shfl_down(s, o); ss += __shfl_down(ss, o); }
    __shared__ float rs[4], rss[4];
    const int wid = tid >> 6, lane = tid & 63;
    if (lane == 0) { rs[wid] = s; rss[wid] = ss; }
    __syncthreads();
    if (tid == 0) {
        float a = 0.f, c = 0.f;
        for (int i = 0; i < 4; i++) { a += rs[i]; c += rss[i]; }
        rs[0] = a; rss[0] = c;
    }
    __syncthreads();
    const float mean = rs[0] / D;
    const float var  = rss[0] / D - mean * mean;
    const float inv  = rsqrtf(fmaxf(var, 0.f) + 1e-6f);
#pragma unroll
    for (int i = 0; i < PT; i++) {
        const int idx = tid + i * 256;
        yr[idx] = f2b((vals[i] - mean) * inv * g[idx] + b[idx]);
    }
}

// ---------------- fp32 -> bf16 elementwise (n % 1024 == 0) ----------------
__global__ __launch_bounds__(256) void conv_kernel(const float* __restrict__ x,
                                                   ushort_t* __restrict__ y)
{
    const int i = (blockIdx.x * 256 + threadIdx.x) * 4;
    const float4 v = *(const float4*)&x[i];
    y[i + 0] = f2b(v.x); y[i + 1] = f2b(v.y); y[i + 2] = f2b(v.z); y[i + 3] = f2b(v.w);
}

// ---------------- W[K,N] f32 -> Wt[N,K] bf16 (transpose+convert) ----------------
__global__ __launch_bounds__(256) void tconv_kernel(const float* __restrict__ W,
                                                    ushort_t* __restrict__ Wt,
                                                    int K, int N)
{
    __shared__ float tile[32][33];
    const int tid = threadIdx.x;
    const int tx = tid & 31, ty = tid >> 5;      // 32 x 8
    const int n0 = blockIdx.x * 32, k0 = blockIdx.y * 32;
#pragma unroll
    for (int i = 0; i < 32; i += 8)
        tile[ty + i][tx] = W[(size_t)(k0 + ty + i) * N + n0 + tx];
    __syncthreads();
#pragma unroll
    for (int i = 0; i < 32; i += 8) {
        const int n = n0 + ty + i, k = k0 + tx;
        Wt[(size_t)n * K + k] = f2b(tile[tx][ty + i]);
    }
}

// ---------------- bf16 MFMA GEMM: C[M,N] = A[M,K] @ Bt[N,K]^T + bias ----------------
// 256 threads = 4 waves; wave grid WR x WC; per-wave FM x FN fragments of 16x16.
// OUT_MODE bit0: write f32 Cf, bit1: write bf16 Cb.
template<int FM, int FN, int WR, int WC, int ACT, int OUT_MODE, bool HAS_RES>
__global__ __launch_bounds__(256) void mfma_gemm(const ushort_t* __restrict__ A,
                                                 const ushort_t* __restrict__ Bt,
                                                 const float* __restrict__ bias,
                                                 const float* __restrict__ res,
                                                 float* __restrict__ Cf,
                                                 ushort_t* __restrict__ Cb,
                                                 int M, int N, int K)
{
    constexpr int BM = WR * FM * 16, BN = WC * FN * 16, BK = 32;
    constexpr int ACH = BM / 16, BCH = BN / 16, TCH = ACH + BCH;
    constexpr int CPW = (TCH + 3) / 4;
    __shared__ alignas(16) ushort_t As[BM * BK];
    __shared__ alignas(16) ushort_t Bs[BN * BK];
    const int tid = threadIdx.x, w = tid >> 6, lane = tid & 63;
    const int wr = w / WC, wc = w % WC;
    const int m0 = blockIdx.y * BM, n0 = blockIdx.x * BN;
    const int lrow = lane >> 2, lkb = (lane & 3) * 8;
    const int fr = lane & 15, kg = (lane >> 4) * 8;

    f32x4 acc[FM][FN] = {};

    for (int k0 = 0; k0 < K; k0 += BK) {
        __syncthreads();
#pragma unroll
        for (int t = 0; t < CPW; t++) {
            const int c = w * CPW + t;
            if (c < ACH) {
                const int row = c * 16 + lrow;
                gload_lds16(A + (size_t)(m0 + row) * K + k0 + lkb, As + c * 512);
            } else if (c < TCH) {
                const int cc = c - ACH;
                const int row = cc * 16 + lrow;
                gload_lds16(Bt + (size_t)(n0 + row) * K + k0 + lkb, Bs + cc * 512);
            }
        }
        __syncthreads();
        bf16x8 af[FM], bfr[FN];
#pragma unroll
        for (int i = 0; i < FM; i++)
            af[i] = *(const bf16x8*)(As + (wr * FM * 16 + i * 16 + fr) * 32 + kg);
#pragma unroll
        for (int j = 0; j < FN; j++)
            bfr[j] = *(const bf16x8*)(Bs + (wc * FN * 16 + j * 16 + fr) * 32 + kg);
#pragma unroll
        for (int i = 0; i < FM; i++)
#pragma unroll
            for (int j = 0; j < FN; j++)
                acc[i][j] = __builtin_amdgcn_mfma_f32_16x16x32_bf16(af[i], bfr[j], acc[i][j], 0, 0, 0);
    }

    const int cr = (lane >> 4) * 4, ccol = lane & 15;
#pragma unroll
    for (int i = 0; i < FM; i++) {
#pragma unroll
        for (int j = 0; j < FN; j++) {
#pragma unroll
            for (int q = 0; q < 4; q++) {
                const int m = m0 + wr * FM * 16 + i * 16 + cr + q;
                const int n = n0 + wc * FN * 16 + j * 16 + ccol;
                float v = acc[i][j][q] + bias[n];
                if (ACT == 1) v = gelu_f(v);
                if (HAS_RES) v += res[(size_t)m * N + n];
                if (OUT_MODE & 1) Cf[(size_t)m * N + n] = v;
                if (OUT_MODE & 2) Cb[(size_t)m * N + n] = f2b(v);
            }
        }
    }
}

// ---------------- gate = sigmoid(qc . gw + gb) ----------------
__global__ __launch_bounds__(64) void gate_kernel(const float* __restrict__ qc,
                                                  const float* __restrict__ gw,
                                                  const float* __restrict__ gb,
                                                  float* __restrict__ gate)
{
    const int bt = blockIdx.x;
    const int d = threadIdx.x;
    const float w = gw[d];
    const int b = bt >> 10, t = bt & 1023;
    const float gbv = gb[0];
#pragma unroll
    for (int h = 0; h < Hd; h++) {
        float v = qc[(size_t)bt * BBd + h * 64 + d] * w;
#pragma unroll
        for (int o = 32; o > 0; o >>= 1) v += __shfl_xor(v, o);
        if (d == 0)
            gate[((size_t)b * Hd + h) * Td + t] = 1.f / (1.f + __expf(-(v + gbv)));
    }
}

// ---------------- fused attention (fp32 math, bf16 out) ----------------
// SA: scores = (qc.ksum + qp.kc)*scale + gate*sb, causal. Tiles beyond the
// diagonal are skipped entirely (NT tiles).
template<int D, bool CAUSAL, bool SA>
__global__ __launch_bounds__(256) void attn_kernel(const float* __restrict__ Q,
                                                   const float* __restrict__ Qp,
                                                   const float* __restrict__ Km,
                                                   const float* __restrict__ Kc,
                                                   const float* __restrict__ V,
                                                   const float* __restrict__ gate,
                                                   const float* __restrict__ sb,
                                                   ushort_t* __restrict__ O,
                                                   int Tq, int Tk, float scale)
{
    constexpr int QR = 8, KT = 64, DP = D + 4;
    const int bh = blockIdx.y, b = bh >> 3, h = bh & 7;
    const int q0 = blockIdx.x * QR;
    const int tid = threadIdx.x;
    const int NH = Hd * D;

    __shared__ alignas(16) float Qs[QR][DP];
    __shared__ alignas(16) float Qps[SA ? QR : 1][SA ? DP : 1];
    __shared__ alignas(16) float Kt[KT][DP];
    __shared__ alignas(16) float Kct[SA ? KT : 1][SA ? DP : 1];
    __shared__ float S[QR][1032];
    __shared__ float PS[QR][16][4];
    __shared__ float rsum[QR];

    const size_t qbase = ((size_t)b * Tq) * NH + (size_t)h * D;
    const size_t kbase = ((size_t)b * Tk) * NH + (size_t)h * D;

    const int NT = CAUSAL ? (q0 / KT + 1) : (Tk / KT);
    const int KTOT = NT * KT;

    for (int idx = tid; idx < QR * (D / 4); idx += 256) {
        const int r = idx / (D / 4), d4 = (idx % (D / 4)) * 4;
        *(float4*)&Qs[r][d4] = *(const float4*)&Q[qbase + (size_t)(q0 + r) * NH + d4];
        if constexpr (SA)
            *(float4*)&Qps[r][d4] = *(const float4*)&Qp[qbase + (size_t)(q0 + r) * NH + d4];
    }

    // ---- scores ----
    for (int t = 0; t < NT; t++) {
        const int k0 = t * KT;
        __syncthreads();
        for (int idx = tid; idx < KT * (D / 4); idx += 256) {
            const int r = idx / (D / 4), d4 = (idx % (D / 4)) * 4;
            *(float4*)&Kt[r][d4] = *(const float4*)&Km[kbase + (size_t)(k0 + r) * NH + d4];
            if constexpr (SA)
                *(float4*)&Kct[r][d4] = *(const float4*)&Kc[kbase + (size_t)(k0 + r) * NH + d4];
        }
        __syncthreads();
#pragma unroll
        for (int pp = 0; pp < 2; pp++) {
            const int p = tid + pp * 256;
            const int r = p >> 6, kk = p & 63;
            const int q = q0 + r, k = k0 + kk;
            float s = 0.f;
#pragma unroll 8
            for (int d = 0; d < D; d += 4) {
                const float4 q4 = *(const float4*)&Qs[r][d];
                const float4 k4 = *(const float4*)&Kt[kk][d];
                s += q4.x * k4.x + q4.y * k4.y + q4.z * k4.z + q4.w * k4.w;
            }
            if constexpr (SA) {
                float s2 = 0.f;
#pragma unroll 8
                for (int d = 0; d < D; d += 4) {
                    const float4 q4 = *(const float4*)&Qps[r][d];
                    const float4 k4 = *(const float4*)&Kct[kk][d];
                    s2 += q4.x * k4.x + q4.y * k4.y + q4.z * k4.z + q4.w * k4.w;
                }
                s = (s + s2) * scale
                  + gate[(size_t)bh * Tq + q] * sb[((size_t)bh * Tq + q) * Tk + k];
            } else {
                s *= scale;
            }
            if (CAUSAL && k > q) s = -INFINITY;
            S[r][k] = s;
        }
    }
    __syncthreads();

    // ---- softmax (one wave per row) ----
    {
        const int wid = tid >> 6, lane = tid & 63;
        for (int r = wid; r < QR; r += 4) {
            float mx = -INFINITY;
            for (int k = lane; k < KTOT; k += 64) mx = fmaxf(mx, S[r][k]);
#pragma unroll
            for (int o = 32; o > 0; o >>= 1) mx = fmaxf(mx, __shfl_xor(mx, o));
            float sum = 0.f;
            for (int k = lane; k < KTOT; k += 64) {
                const float e = __expf(S[r][k] - mx);
                S[r][k] = e; sum += e;
            }
#pragma unroll
            for (int o = 32; o > 0; o >>= 1) sum += __shfl_xor(sum, o);
            if (lane == 0) rsum[r] = sum;
        }
    }

    // ---- PV (float4 over d; D==64 uses 2-way k-split) ----
    int r, d0, klo, khi;
    if constexpr (D == 64) {
        const int ks = tid >> 7;
        r = (tid >> 4) & 7; d0 = (tid & 15) * 4;
        klo = ks * 32; khi = klo + 32;
    } else {
        r = tid >> 5; d0 = (tid & 31) * 4;
        klo = 0; khi = KT;
    }
    float4 acc = make_float4(0.f, 0.f, 0.f, 0.f);
    for (int t = 0; t < NT; t++) {
        const int k0 = t * KT;
        __syncthreads();
        for (int idx = tid; idx < KT * (D / 4); idx += 256) {
            const int rr = idx / (D / 4), d4 = (idx % (D / 4)) * 4;
            *(float4*)&Kt[rr][d4] = *(const float4*)&V[kbase + (size_t)(k0 + rr) * NH + d4];
        }
        __syncthreads();
        for (int kk = klo; kk < khi; kk++) {
            const float s = S[r][k0 + kk];
            const float4 v4 = *(const float4*)&Kt[kk][d0];
            acc.x += s * v4.x; acc.y += s * v4.y; acc.z += s * v4.z; acc.w += s * v4.w;
        }
    }
    if constexpr (D == 64) {
        __syncthreads();
        if (tid >> 7) {
            PS[r][d0 >> 2][0] = acc.x; PS[r][d0 >> 2][1] = acc.y;
            PS[r][d0 >> 2][2] = acc.z; PS[r][d0 >> 2][3] = acc.w;
        }
        __syncthreads();
        if (!(tid >> 7)) {
            acc.x += PS[r][d0 >> 2][0]; acc.y += PS[r][d0 >> 2][1];
            acc.z += PS[r][d0 >> 2][2]; acc.w += PS[r][d0 >> 2][3];
            const float inv = 1.f / rsum[r];
            ushort_t* o = O + qbase + (size_t)(q0 + r) * NH + d0;
            o[0] = f2b(acc.x * inv); o[1] = f2b(acc.y * inv);
            o[2] = f2b(acc.z * inv); o[3] = f2b(acc.w * inv);
        }
    } else {
        const float inv = 1.f / rsum[r];
        ushort_t* o = O + qbase + (size_t)(q0 + r) * NH + d0;
        o[0] = f2b(acc.x * inv); o[1] = f2b(acc.y * inv);
        o[2] = f2b(acc.z * inv); o[3] = f2b(acc.w * inv);
    }
}

// ---------------------------------------------------------------
extern "C" void kernel_launch(void* const* d_in, const int* in_sizes, int n_in,
                              void* d_out, int out_size, void* d_ws, size_t ws_size,
                              hipStream_t stream)
{
    const float* layout_content = (const float*)d_in[0];
    const float* text_x         = (const float*)d_in[1];
    const float* text_memory    = (const float*)d_in[2];
    const float* spatial_bias   = (const float*)d_in[3];
    const float* layout_pos     = (const float*)d_in[4];
    // d_in[5] trg_mask (tril -> analytic), d_in[6] src_mask (all ones -> no-op)
    const float* sa_q_w = (const float*)d_in[7];   const float* sa_q_b = (const float*)d_in[8];
    const float* sa_k_w = (const float*)d_in[9];   const float* sa_k_b = (const float*)d_in[10];
    const float* sa_v_w = (const float*)d_in[11];  const float* sa_v_b = (const float*)d_in[12];
    const float* sa_pk_w = (const float*)d_in[13]; const float* sa_pk_b = (const float*)d_in[14];
    const float* sa_pq_w = (const float*)d_in[15]; const float* sa_pq_b = (const float*)d_in[16];
    const float* sa_o_w = (const float*)d_in[17];  const float* sa_o_b = (const float*)d_in[18];
    const float* lt_q_w = (const float*)d_in[19];  const float* lt_q_b = (const float*)d_in[20];
    const float* lt_k_w = (const float*)d_in[21];  const float* lt_k_b = (const float*)d_in[22];
    const float* lt_v_w = (const float*)d_in[23];  const float* lt_v_b = (const float*)d_in[24];
    const float* lt_o_w = (const float*)d_in[25];  const float* lt_o_b = (const float*)d_in[26];
    const float* tl_q_w = (const float*)d_in[27];  const float* tl_q_b = (const float*)d_in[28];
    const float* tl_k_w = (const float*)d_in[29];  const float* tl_k_b = (const float*)d_in[30];
    const float* tl_v_w = (const float*)d_in[31];  const float* tl_v_b = (const float*)d_in[32];
    const float* tl_o_w = (const float*)d_in[33];  const float* tl_o_b = (const float*)d_in[34];
    const float* ltp_w = (const float*)d_in[35];   const float* ltp_b = (const float*)d_in[36];
    const float* tlp_w = (const float*)d_in[37];   const float* tlp_b = (const float*)d_in[38];
    const float* lf1_w = (const float*)d_in[39];   const float* lf1_b = (const float*)d_in[40];
    const float* lf2_w = (const float*)d_in[41];   const float* lf2_b = (const float*)d_in[42];
    const float* tf1_w = (const float*)d_in[43];   const float* tf1_b = (const float*)d_in[44];
    const float* tf2_w = (const float*)d_in[45];   const float* tf2_b = (const float*)d_in[46];
    const float* sa_g_w = (const float*)d_in[47];  const float* sa_g_b = (const float*)d_in[48];
    const float* ln1_g = (const float*)d_in[49];   const float* ln1_b = (const float*)d_in[50];
    const float* ln2_g = (const float*)d_in[51];   const float* ln2_b = (const float*)d_in[52];
    const float* tn1_g = (const float*)d_in[53];   const float* tn1_b = (const float*)d_in[54];
    const float* lfn_g = (const float*)d_in[55];   const float* lfn_b = (const float*)d_in[56];
    const float* tfn_g = (const float*)d_in[57];   const float* tfn_b = (const float*)d_in[58];

    float* out = (float*)d_out;
    float* layout_out = out;                        // [4,1024,512] f32
    float* text_out   = out + (size_t)ROWSd * BBd;  // [4,1024,1024] f32

    // ---- bump allocator over d_ws ----
    char* p = (char*)d_ws;
    auto alloc = [&](size_t bytes) { void* r = (void*)p; p += (bytes + 255) & ~(size_t)255; return r; };
    const size_t R = ROWSd;

    float*  Qbf  = (float*)alloc(R * 1024 * 4);   // 16MB  (also HBb part 1)
    float*  Kbf  = (float*)alloc(R * 1024 * 4);   // 16MB  (also HBb part 2; contiguous with Qbf)
    float*  Vbf  = (float*)alloc(R * 1024 * 4);   // 16MB
    ushort_t* HBb = (ushort_t*)Qbf;               // [4096,4096] bf16 alias (lives 17-18, 27-28)
    float*  KSf  = (float*)alloc(R * 512 * 4);    // 8MB
    float*  QPf  = (float*)alloc(R * 512 * 4);    // 8MB
    float*  GATEf= (float*)alloc((size_t)Bd * Hd * Td * 4);
    ushort_t* CTXb = (ushort_t*)alloc(R * 1024 * 2); // 8MB  (also LOb alias)
    ushort_t* LOb  = CTXb;                        // layout_out bf16 [4096,512]
    float*  LSOf = (float*)alloc(R * 512 * 4);    // 8MB
    float*  LPREf= (float*)alloc(R * 512 * 4);    // 8MB
    float*  TPREf= (float*)alloc(R * 1024 * 4);   // 16MB
    ushort_t* XNb  = (ushort_t*)alloc(R * 1024 * 2); // 8MB
    ushort_t* LPb  = (ushort_t*)alloc(R * 512 * 2);  // 4MB  (also TLOb alias)
    ushort_t* TLOb = LPb;
    ushort_t* TMb  = (ushort_t*)alloc(R * 1024 * 2); // 8MB  (also LTOb alias)
    ushort_t* LTOb = TMb;

    // transposed bf16 weights [N,K]
    auto wt = [&](int K, int N) { return (ushort_t*)alloc((size_t)K * N * 2); };
    ushort_t* sa_q_t = wt(512, 512);  ushort_t* sa_k_t = wt(512, 512);  ushort_t* sa_v_t = wt(512, 512);
    ushort_t* sa_pk_t = wt(512, 512); ushort_t* sa_pq_t = wt(512, 512); ushort_t* sa_o_t = wt(512, 512);
    ushort_t* lt_q_t = wt(512, 1024); ushort_t* lt_k_t = wt(1024, 1024);
    ushort_t* lt_v_t = wt(1024, 1024); ushort_t* lt_o_t = wt(1024, 1024);
    ushort_t* tl_q_t = wt(1024, 512); ushort_t* tl_k_t = wt(512, 512);
    ushort_t* tl_v_t = wt(512, 512);  ushort_t* tl_o_t = wt(512, 512);
    ushort_t* ltp_t = wt(1024, 512);  ushort_t* tlp_t = wt(512, 1024);
    ushort_t* lf1_t = wt(512, 4096);  ushort_t* lf2_t = wt(4096, 512);
    ushort_t* tf1_t = wt(1024, 4096); ushort_t* tf2_t = wt(4096, 1024);

    const dim3 blk(256);

    // ---- weight transpose+convert ----
    auto tc = [&](const float* W, ushort_t* Wt, int K, int N) {
        tconv_kernel<<<dim3(N / 32, K / 32), blk, 0, stream>>>(W, Wt, K, N);
    };
    tc(sa_q_w, sa_q_t, 512, 512);   tc(sa_k_w, sa_k_t, 512, 512);   tc(sa_v_w, sa_v_t, 512, 512);
    tc(sa_pk_w, sa_pk_t, 512, 512); tc(sa_pq_w, sa_pq_t, 512, 512); tc(sa_o_w, sa_o_t, 512, 512);
    tc(lt_q_w, lt_q_t, 512, 1024);  tc(lt_k_w, lt_k_t, 1024, 1024);
    tc(lt_v_w, lt_v_t, 1024, 1024); tc(lt_o_w, lt_o_t, 1024, 1024);
    tc(tl_q_w, tl_q_t, 1024, 512);  tc(tl_k_w, tl_k_t, 512, 512);
    tc(tl_v_w, tl_v_t, 512, 512);   tc(tl_o_w, tl_o_t, 512, 512);
    tc(ltp_w, ltp_t, 1024, 512);    tc(tlp_w, tlp_t, 512, 1024);
    tc(lf1_w, lf1_t, 512, 4096);    tc(lf2_w, lf2_t, 4096, 512);
    tc(tf1_w, tf1_t, 1024, 4096);   tc(tf2_w, tf2_t, 4096, 1024);

    // ---- activation input conversions ----
    conv_kernel<<<dim3(R * 512 / 1024), blk, 0, stream>>>(layout_pos, LPb);
    conv_kernel<<<dim3(R * 1024 / 1024), blk, 0, stream>>>(text_memory, TMb);

    // GEMM launchers: N=512 -> <2,2,1,4> (32x128, 512 wg); N=1024 -> <4,2,1,4> (64x128, 512 wg);
    // N=4096 -> <4,4,2,2> (128x128, 1024 wg)
#define G512(ACT, OM, RES, Aa, Bb, bb, rr, cf, cb, K) \
    mfma_gemm<2, 2, 1, 4, ACT, OM, RES><<<dim3(512 / 128, ROWSd / 32), blk, 0, stream>>>(Aa, Bb, bb, rr, cf, cb, ROWSd, 512, K)
#define G1024(ACT, OM, RES, Aa, Bb, bb, rr, cf, cb, K) \
    mfma_gemm<4, 2, 1, 4, ACT, OM, RES><<<dim3(1024 / 128, ROWSd / 64), blk, 0, stream>>>(Aa, Bb, bb, rr, cf, cb, ROWSd, 1024, K)
#define G4096(ACT, OM, RES, Aa, Bb, bb, rr, cf, cb, K) \
    mfma_gemm<4, 4, 2, 2, ACT, OM, RES><<<dim3(4096 / 128, ROWSd / 128), blk, 0, stream>>>(Aa, Bb, bb, rr, cf, cb, ROWSd, 4096, K)

    // ===== layout self-attention =====
    ln_kernel<512><<<dim3(ROWSd), blk, 0, stream>>>(layout_content, ln1_g, ln1_b, XNb);
    G512(0, 1, false, XNb, sa_q_t, sa_q_b, nullptr, Qbf, nullptr, 512);
    G512(0, 1, false, XNb, sa_k_t, sa_k_b, nullptr, Kbf, nullptr, 512);
    G512(0, 1, false, XNb, sa_v_t, sa_v_b, nullptr, Vbf, nullptr, 512);
    G512(0, 1, false, LPb, sa_pq_t, sa_pq_b, nullptr, QPf, nullptr, 512);
    G512(0, 1, true,  LPb, sa_pk_t, sa_pk_b, Kbf, KSf, nullptr, 512);   // ksum = kp + kc
    gate_kernel<<<dim3(ROWSd), dim3(64), 0, stream>>>(Qbf, sa_g_w, sa_g_b, GATEf);
    attn_kernel<64, true, true><<<dim3(Td / 8, Bd * Hd), blk, 0, stream>>>(
        Qbf, QPf, KSf, Kbf, Vbf, GATEf, spatial_bias, CTXb, Td, Td, 0.125f);
    G512(0, 1, true, CTXb, sa_o_t, sa_o_b, layout_content, LSOf, nullptr, 512);

    // ===== layout -> text cross attention =====
    ln_kernel<512><<<dim3(ROWSd), blk, 0, stream>>>(LSOf, ln2_g, ln2_b, XNb);
    G1024(0, 1, false, XNb, lt_q_t, lt_q_b, nullptr, Qbf, nullptr, 512);
    G1024(0, 1, false, TMb, lt_k_t, lt_k_b, nullptr, Kbf, nullptr, 1024);
    G1024(0, 1, false, TMb, lt_v_t, lt_v_b, nullptr, Vbf, nullptr, 1024);
    attn_kernel<128, false, false><<<dim3(Td / 8, Bd * Hd), blk, 0, stream>>>(
        Qbf, nullptr, Kbf, nullptr, Vbf, nullptr, nullptr, CTXb, Td, Ld, 0.08838834764831845f);
    G1024(0, 2, false, CTXb, lt_o_t, lt_o_b, nullptr, nullptr, LTOb, 1024);
    G512(0, 1, true, LTOb, ltp_t, ltp_b, LSOf, LPREf, nullptr, 1024);

    // ===== layout FFN =====
    ln_kernel<512><<<dim3(ROWSd), blk, 0, stream>>>(LPREf, lfn_g, lfn_b, XNb);
    G4096(1, 2, false, XNb, lf1_t, lf1_b, nullptr, nullptr, HBb, 512);
    G512(0, 3, true, HBb, lf2_t, lf2_b, LPREf, layout_out, LOb, 4096);

    // ===== text -> layout cross attention =====
    ln_kernel<1024><<<dim3(ROWSd), blk, 0, stream>>>(text_x, tn1_g, tn1_b, XNb);
    G512(0, 1, false, XNb, tl_q_t, tl_q_b, nullptr, Qbf, nullptr, 1024);
    G512(0, 1, false, LOb, tl_k_t, tl_k_b, nullptr, Kbf, nullptr, 512);
    G512(0, 1, false, LOb, tl_v_t, tl_v_b, nullptr, Vbf, nullptr, 512);
    attn_kernel<64, false, false><<<dim3(Td / 8, Bd * Hd), blk, 0, stream>>>(
        Qbf, nullptr, Kbf, nullptr, Vbf, nullptr, nullptr, CTXb, Td, Td, 0.125f);
    G512(0, 2, false, CTXb, tl_o_t, tl_o_b, nullptr, nullptr, TLOb, 512);
    G1024(0, 1, true, TLOb, tlp_t, tlp_b, text_x, TPREf, nullptr, 512);

    // ===== text FFN =====
    ln_kernel<1024><<<dim3(ROWSd), blk, 0, stream>>>(TPREf, tfn_g, tfn_b, XNb);
    G4096(1, 2, false, XNb, tf1_t, tf1_b, nullptr, nullptr, HBb, 1024);
    G1024(0, 1, true, HBb, tf2_t, tf2_b, TPREf, text_out, nullptr, 4096);

#undef G512
#undef G1024
#undef G4096
}

// Round 4
// 1249.702 us; speedup vs baseline: 4.8268x; 2.2838x over previous
//
#include <hip/hip_runtime.h>

#define Bd 4
#define Td 1024
#define Ld 1024
#define HIDd 1024
#define BBd 512
#define FFd 4096
#define Hd 8
#define ROWSd 4096   // B*T = B*L

typedef unsigned short ushort_t;
typedef _Float16 f16;
typedef __attribute__((ext_vector_type(8))) short bf16x8;
typedef __attribute__((ext_vector_type(8))) _Float16 f16x8;
typedef __attribute__((ext_vector_type(4))) _Float16 f16x4;
typedef __attribute__((ext_vector_type(4))) float f32x4;

__device__ __forceinline__ float gelu_f(float x) {
    return 0.5f * x * (1.f + tanhf(0.7978845608028654f * (x + 0.044715f * x * x * x)));
}

__device__ __forceinline__ ushort_t f2b(float x) {
    union { float f; unsigned u; } v; v.f = x;
    unsigned r = v.u + 0x7fffu + ((v.u >> 16) & 1u);   // RTNE
    return (ushort_t)(r >> 16);
}

__device__ __forceinline__ void gload_lds16(const ushort_t* g, ushort_t* l) {
    __builtin_amdgcn_global_load_lds((__attribute__((address_space(1))) void*)(void*)g,
                                     (__attribute__((address_space(3))) void*)l,
                                     16, 0, 0);
}

// ---------------- LayerNorm: one block per row, bf16 out ----------------
template<int D>
__global__ __launch_bounds__(256) void ln_kernel(const float* __restrict__ x,
                                                 const float* __restrict__ g,
                                                 const float* __restrict__ b,
                                                 ushort_t* __restrict__ y)
{
    const int row = blockIdx.x;
    const int tid = threadIdx.x;
    const float* xr = x + (size_t)row * D;
    ushort_t* yr = y + (size_t)row * D;
    constexpr int PT = D / 256;
    float vals[PT];
    float s = 0.f, ss = 0.f;
#pragma unroll
    for (int i = 0; i < PT; i++) {
        float v = xr[tid + i * 256];
        vals[i] = v; s += v; ss += v * v;
    }
#pragma unroll
    for (int o = 32; o > 0; o >>= 1) { s += __shfl_down(s, o); ss += __shfl_down(ss, o); }
    __shared__ float rs[4], rss[4];
    const int wid = tid >> 6, lane = tid & 63;
    if (lane == 0) { rs[wid] = s; rss[wid] = ss; }
    __syncthreads();
    if (tid == 0) {
        float a = 0.f, c = 0.f;
        for (int i = 0; i < 4; i++) { a += rs[i]; c += rss[i]; }
        rs[0] = a; rss[0] = c;
    }
    __syncthreads();
    const float mean = rs[0] / D;
    const float var  = rss[0] / D - mean * mean;
    const float inv  = rsqrtf(fmaxf(var, 0.f) + 1e-6f);
#pragma unroll
    for (int i = 0; i < PT; i++) {
        const int idx = tid + i * 256;
        yr[idx] = f2b((vals[i] - mean) * inv * g[idx] + b[idx]);
    }
}

// ---------------- fp32 -> bf16 elementwise ----------------
__global__ __launch_bounds__(256) void conv_kernel(const float* __restrict__ x,
                                                   ushort_t* __restrict__ y)
{
    const int i = (blockIdx.x * 256 + threadIdx.x) * 4;
    const float4 v = *(const float4*)&x[i];
    y[i + 0] = f2b(v.x); y[i + 1] = f2b(v.y); y[i + 2] = f2b(v.z); y[i + 3] = f2b(v.w);
}

// ---------------- W[K,N] f32 -> Wt[N,K] bf16 ----------------
__global__ __launch_bounds__(256) void tconv_kernel(const float* __restrict__ W,
                                                    ushort_t* __restrict__ Wt,
                                                    int K, int N)
{
    __shared__ float tile[32][33];
    const int tid = threadIdx.x;
    const int tx = tid & 31, ty = tid >> 5;
    const int n0 = blockIdx.x * 32, k0 = blockIdx.y * 32;
#pragma unroll
    for (int i = 0; i < 32; i += 8)
        tile[ty + i][tx] = W[(size_t)(k0 + ty + i) * N + n0 + tx];
    __syncthreads();
#pragma unroll
    for (int i = 0; i < 32; i += 8) {
        const int n = n0 + ty + i, k = k0 + tx;
        Wt[(size_t)n * K + k] = f2b(tile[tx][ty + i]);
    }
}

// ---------------- bf16 MFMA GEMM: C[M,N] = A[M,K] @ Bt[N,K]^T + bias ----------------
// OMODE: 1=f32, 2=bf16, 3=f32+bf16, 4=f16, 5=f16 transposed [N][M]
// RESM:  0=none, 1=f32 residual, 2=f16 residual
template<int FM, int FN, int WR, int WC, int ACT, int OMODE, int RESM>
__global__ __launch_bounds__(256) void mfma_gemm(const ushort_t* __restrict__ A,
                                                 const ushort_t* __restrict__ Bt,
                                                 const float* __restrict__ bias,
                                                 const void* __restrict__ resv,
                                                 float* __restrict__ Cf,
                                                 ushort_t* __restrict__ Cb,
                                                 f16* __restrict__ Ch,
                                                 int M, int N, int K)
{
    constexpr int BM = WR * FM * 16, BN = WC * FN * 16, BK = 32;
    constexpr int ACH = BM / 16, BCH = BN / 16, TCH = ACH + BCH;
    constexpr int CPW = (TCH + 3) / 4;
    __shared__ alignas(16) ushort_t As[BM * BK];
    __shared__ alignas(16) ushort_t Bs[BN * BK];
    const int tid = threadIdx.x, w = tid >> 6, lane = tid & 63;
    const int wr = w / WC, wc = w % WC;
    const int m0 = blockIdx.y * BM, n0 = blockIdx.x * BN;
    const int lrow = lane >> 2, lkb = (lane & 3) * 8;
    const int fr = lane & 15, kg = (lane >> 4) * 8;

    f32x4 acc[FM][FN] = {};

    for (int k0 = 0; k0 < K; k0 += BK) {
        __syncthreads();
#pragma unroll
        for (int t = 0; t < CPW; t++) {
            const int c = w * CPW + t;
            if (c < ACH) {
                const int row = c * 16 + lrow;
                gload_lds16(A + (size_t)(m0 + row) * K + k0 + lkb, As + c * 512);
            } else if (c < TCH) {
                const int cc = c - ACH;
                const int row = cc * 16 + lrow;
                gload_lds16(Bt + (size_t)(n0 + row) * K + k0 + lkb, Bs + cc * 512);
            }
        }
        __syncthreads();
        bf16x8 af[FM], bfr[FN];
#pragma unroll
        for (int i = 0; i < FM; i++)
            af[i] = *(const bf16x8*)(As + (wr * FM * 16 + i * 16 + fr) * 32 + kg);
#pragma unroll
        for (int j = 0; j < FN; j++)
            bfr[j] = *(const bf16x8*)(Bs + (wc * FN * 16 + j * 16 + fr) * 32 + kg);
#pragma unroll
        for (int i = 0; i < FM; i++)
#pragma unroll
            for (int j = 0; j < FN; j++)
                acc[i][j] = __builtin_amdgcn_mfma_f32_16x16x32_bf16(af[i], bfr[j], acc[i][j], 0, 0, 0);
    }

    const int cr = (lane >> 4) * 4, ccol = lane & 15;
#pragma unroll
    for (int i = 0; i < FM; i++) {
#pragma unroll
        for (int j = 0; j < FN; j++) {
            const int n = n0 + wc * FN * 16 + j * 16 + ccol;
            const int mb = m0 + wr * FM * 16 + i * 16 + cr;
            float vv[4];
#pragma unroll
            for (int q = 0; q < 4; q++) {
                float v = acc[i][j][q] + bias[n];
                if (ACT == 1) v = gelu_f(v);
                if (RESM == 1) v += ((const float*)resv)[(size_t)(mb + q) * N + n];
                if (RESM == 2) v += (float)((const f16*)resv)[(size_t)(mb + q) * N + n];
                vv[q] = v;
            }
            if (OMODE == 1 || OMODE == 3) {   // (fixed: was OMODE & 1, which also hit OMODE==5 -> null Cf)
#pragma unroll
                for (int q = 0; q < 4; q++) Cf[(size_t)(mb + q) * N + n] = vv[q];
            }
            if (OMODE == 2 || OMODE == 3) {
#pragma unroll
                for (int q = 0; q < 4; q++) Cb[(size_t)(mb + q) * N + n] = f2b(vv[q]);
            }
            if (OMODE == 4) {
#pragma unroll
                for (int q = 0; q < 4; q++) Ch[(size_t)(mb + q) * N + n] = (f16)vv[q];
            }
            if (OMODE == 5) {
                f16x4 pk = { (f16)vv[0], (f16)vv[1], (f16)vv[2], (f16)vv[3] };
                *(f16x4*)&Ch[(size_t)n * M + mb] = pk;
            }
        }
    }
}

// ---------------- gate = sigmoid(qc . gw + gb) ----------------
__global__ __launch_bounds__(64) void gate_kernel(const f16* __restrict__ qc,
                                                  const float* __restrict__ gw,
                                                  const float* __restrict__ gb,
                                                  float* __restrict__ gate)
{
    const int bt = blockIdx.x;
    const int d = threadIdx.x;
    const float w = gw[d];
    const int b = bt >> 10, t = bt & 1023;
    const float gbv = gb[0];
#pragma unroll
    for (int h = 0; h < Hd; h++) {
        float v = (float)qc[(size_t)bt * BBd + h * 64 + d] * w;
#pragma unroll
        for (int o = 32; o > 0; o >>= 1) v += __shfl_xor(v, o);
        if (d == 0)
            gate[((size_t)b * Hd + h) * Td + t] = 1.f / (1.f + __expf(-(v + gbv)));
    }
}

// ---------------- MFMA flash attention ----------------
// Q,K fp16 [B*T][H*D]; Vt fp16 [H*D][B*Tk] (pre-transposed); out bf16 [B*T][H*D].
// 4 waves x 16 q-rows; KT=64 k-tiles; online softmax in C-fragment layout.
// SA: S = (qc.ksum + qp.kc)*scale + gate*sb, causal.
template<int D, bool CAUSAL, bool SA>
__global__ __launch_bounds__(256) void attn_mfma(const f16* __restrict__ Q,
                                                 const f16* __restrict__ Qp,
                                                 const f16* __restrict__ Km,
                                                 const f16* __restrict__ Kc,
                                                 const f16* __restrict__ Vt,
                                                 const float* __restrict__ gate,
                                                 const float* __restrict__ sb,
                                                 ushort_t* __restrict__ O,
                                                 int Tq, int Tk, float scale)
{
    constexpr int KT = 64, QB = 64, PAD = 8;
    constexpr int NS = D / 32;          // QK^T contraction slots
    constexpr int NDF = D / 16;         // output col fragments
    constexpr int KROW = D + PAD;       // Ks row stride (f16)
    constexpr int VROW = KT + PAD;      // Vts/Pw row stride (f16)
    const int bh = blockIdx.y, b = bh >> 3, h = bh & 7;
    const int q0 = blockIdx.x * QB;
    const int tid = threadIdx.x, w = tid >> 6, lane = tid & 63;
    const int NH = Hd * D;
    const int qw0 = q0 + w * 16;
    const int fr = lane & 15;           // A row / B col / C col
    const int kg8 = (lane >> 4) * 8;    // A/B k-offset
    const int cr4 = (lane >> 4) * 4;    // C row base

    __shared__ alignas(16) f16 Ks[KT * KROW];
    __shared__ alignas(16) f16 Kcs[SA ? KT * KROW : 8];
    __shared__ alignas(16) f16 Vts[D * VROW];
    __shared__ alignas(16) f16 Pw[4][16 * VROW];

    const size_t qb = ((size_t)b * Tq) * NH + (size_t)h * D;
    const size_t kb = ((size_t)b * Tk) * NH + (size_t)h * D;

    // Q fragments straight from global (tiny, once per block)
    f16x8 aq[NS], ap[SA ? NS : 1];
#pragma unroll
    for (int s = 0; s < NS; s++) {
        aq[s] = *(const f16x8*)&Q[qb + (size_t)(qw0 + fr) * NH + s * 32 + kg8];
        if constexpr (SA)
            ap[s] = *(const f16x8*)&Qp[qb + (size_t)(qw0 + fr) * NH + s * 32 + kg8];
    }
    float gq[4];
    if constexpr (SA) {
#pragma unroll
        for (int r = 0; r < 4; r++)
            gq[r] = gate[(size_t)bh * Tq + qw0 + cr4 + r];
    }

    float m[4], l[4];
    f32x4 oacc[NDF] = {};
#pragma unroll
    for (int r = 0; r < 4; r++) { m[r] = -1e30f; l[r] = 0.f; }

    const int NT = CAUSAL ? (q0 / KT + 1) : (Tk / KT);
    for (int t = 0; t < NT; t++) {
        const int k0 = t * KT;
        // ---- stage K (and Kc), Vt into LDS ----
        constexpr int KCH = KT * D / 8;
        for (int i = tid; i < KCH; i += 256) {
            const int row = i / (D / 8), c8 = (i % (D / 8)) * 8;
            *(f16x8*)&Ks[row * KROW + c8] = *(const f16x8*)&Km[kb + (size_t)(k0 + row) * NH + c8];
            if constexpr (SA)
                *(f16x8*)&Kcs[row * KROW + c8] = *(const f16x8*)&Kc[kb + (size_t)(k0 + row) * NH + c8];
        }
        constexpr int VCH = D * KT / 8;
        for (int i = tid; i < VCH; i += 256) {
            const int d = i / (KT / 8), c8 = (i % (KT / 8)) * 8;
            *(f16x8*)&Vts[d * VROW + c8] =
                *(const f16x8*)&Vt[(size_t)(h * D + d) * ((size_t)Bd * Tk) + (size_t)b * Tk + k0 + c8];
        }
        __syncthreads();

        // ---- S fragments: 4 col-frags of 16 k ----
        float pv[4][4];
#pragma unroll
        for (int kf = 0; kf < 4; kf++) {
            f32x4 sacc = {};
#pragma unroll
            for (int s = 0; s < NS; s++) {
                const f16x8 bk = *(const f16x8*)&Ks[(kf * 16 + fr) * KROW + s * 32 + kg8];
                sacc = __builtin_amdgcn_mfma_f32_16x16x32_f16(aq[s], bk, sacc, 0, 0, 0);
            }
            if constexpr (SA) {
#pragma unroll
                for (int s = 0; s < NS; s++) {
                    const f16x8 bkc = *(const f16x8*)&Kcs[(kf * 16 + fr) * KROW + s * 32 + kg8];
                    sacc = __builtin_amdgcn_mfma_f32_16x16x32_f16(ap[s], bkc, sacc, 0, 0, 0);
                }
            }
            const int k = k0 + kf * 16 + fr;
#pragma unroll
            for (int r = 0; r < 4; r++) {
                const int q = qw0 + cr4 + r;
                float v = sacc[r] * scale;
                if constexpr (SA)
                    v += gq[r] * sb[((size_t)bh * Tq + q) * Tk + k];
                if (CAUSAL && k > q) v = -1e30f;
                pv[kf][r] = v;
            }
        }

        // ---- online softmax update (per lane: 4 rows x 4 cols) ----
#pragma unroll
        for (int r = 0; r < 4; r++) {
            float mx = fmaxf(fmaxf(pv[0][r], pv[1][r]), fmaxf(pv[2][r], pv[3][r]));
            mx = fmaxf(mx, __shfl_xor(mx, 1));
            mx = fmaxf(mx, __shfl_xor(mx, 2));
            mx = fmaxf(mx, __shfl_xor(mx, 4));
            mx = fmaxf(mx, __shfl_xor(mx, 8));
            const float mn = fmaxf(m[r], mx);
            const float fs = __expf(m[r] - mn);
            m[r] = mn;
            float ls = 0.f;
#pragma unroll
            for (int kf = 0; kf < 4; kf++) {
                const float p = __expf(pv[kf][r] - mn);
                pv[kf][r] = p; ls += p;
            }
            ls += __shfl_xor(ls, 1);
            ls += __shfl_xor(ls, 2);
            ls += __shfl_xor(ls, 4);
            ls += __shfl_xor(ls, 8);
            l[r] = l[r] * fs + ls;
#pragma unroll
            for (int df = 0; df < NDF; df++) oacc[df][r] *= fs;
        }

        // ---- P -> LDS (per-wave private) ----
#pragma unroll
        for (int kf = 0; kf < 4; kf++)
#pragma unroll
            for (int r = 0; r < 4; r++)
                Pw[w][(cr4 + r) * VROW + kf * 16 + fr] = (f16)pv[kf][r];
        asm volatile("s_waitcnt lgkmcnt(0)" ::: "memory");
        __builtin_amdgcn_sched_barrier(0);

        // ---- PV ----
#pragma unroll
        for (int s = 0; s < KT / 32; s++) {
            const f16x8 pa = *(const f16x8*)&Pw[w][fr * VROW + s * 32 + kg8];
#pragma unroll
            for (int df = 0; df < NDF; df++) {
                const f16x8 vb = *(const f16x8*)&Vts[(df * 16 + fr) * VROW + s * 32 + kg8];
                oacc[df] = __builtin_amdgcn_mfma_f32_16x16x32_f16(pa, vb, oacc[df], 0, 0, 0);
            }
        }
        __syncthreads();
    }

    // ---- epilogue: O /= l, write bf16 ----
#pragma unroll
    for (int r = 0; r < 4; r++) {
        const float inv = 1.f / l[r];
        const size_t rowb = qb + (size_t)(qw0 + cr4 + r) * NH;
#pragma unroll
        for (int df = 0; df < NDF; df++)
            O[rowb + df * 16 + fr] = f2b(oacc[df][r] * inv);
    }
}

// ---------------------------------------------------------------
extern "C" void kernel_launch(void* const* d_in, const int* in_sizes, int n_in,
                              void* d_out, int out_size, void* d_ws, size_t ws_size,
                              hipStream_t stream)
{
    const float* layout_content = (const float*)d_in[0];
    const float* text_x         = (const float*)d_in[1];
    const float* text_memory    = (const float*)d_in[2];
    const float* spatial_bias   = (const float*)d_in[3];
    const float* layout_pos     = (const float*)d_in[4];
    // d_in[5] trg_mask (tril -> analytic), d_in[6] src_mask (all ones -> no-op)
    const float* sa_q_w = (const float*)d_in[7];   const float* sa_q_b = (const float*)d_in[8];
    const float* sa_k_w = (const float*)d_in[9];   const float* sa_k_b = (const float*)d_in[10];
    const float* sa_v_w = (const float*)d_in[11];  const float* sa_v_b = (const float*)d_in[12];
    const float* sa_pk_w = (const float*)d_in[13]; const float* sa_pk_b = (const float*)d_in[14];
    const float* sa_pq_w = (const float*)d_in[15]; const float* sa_pq_b = (const float*)d_in[16];
    const float* sa_o_w = (const float*)d_in[17];  const float* sa_o_b = (const float*)d_in[18];
    const float* lt_q_w = (const float*)d_in[19];  const float* lt_q_b = (const float*)d_in[20];
    const float* lt_k_w = (const float*)d_in[21];  const float* lt_k_b = (const float*)d_in[22];
    const float* lt_v_w = (const float*)d_in[23];  const float* lt_v_b = (const float*)d_in[24];
    const float* lt_o_w = (const float*)d_in[25];  const float* lt_o_b = (const float*)d_in[26];
    const float* tl_q_w = (const float*)d_in[27];  const float* tl_q_b = (const float*)d_in[28];
    const float* tl_k_w = (const float*)d_in[29];  const float* tl_k_b = (const float*)d_in[30];
    const float* tl_v_w = (const float*)d_in[31];  const float* tl_v_b = (const float*)d_in[32];
    const float* tl_o_w = (const float*)d_in[33];  const float* tl_o_b = (const float*)d_in[34];
    const float* ltp_w = (const float*)d_in[35];   const float* ltp_b = (const float*)d_in[36];
    const float* tlp_w = (const float*)d_in[37];   const float* tlp_b = (const float*)d_in[38];
    const float* lf1_w = (const float*)d_in[39];   const float* lf1_b = (const float*)d_in[40];
    const float* lf2_w = (const float*)d_in[41];   const float* lf2_b = (const float*)d_in[42];
    const float* tf1_w = (const float*)d_in[43];   const float* tf1_b = (const float*)d_in[44];
    const float* tf2_w = (const float*)d_in[45];   const float* tf2_b = (const float*)d_in[46];
    const float* sa_g_w = (const float*)d_in[47];  const float* sa_g_b = (const float*)d_in[48];
    const float* ln1_g = (const float*)d_in[49];   const float* ln1_b = (const float*)d_in[50];
    const float* ln2_g = (const float*)d_in[51];   const float* ln2_b = (const float*)d_in[52];
    const float* tn1_g = (const float*)d_in[53];   const float* tn1_b = (const float*)d_in[54];
    const float* lfn_g = (const float*)d_in[55];   const float* lfn_b = (const float*)d_in[56];
    const float* tfn_g = (const float*)d_in[57];   const float* tfn_b = (const float*)d_in[58];

    float* out = (float*)d_out;
    float* layout_out = out;                        // [4,1024,512] f32
    float* text_out   = out + (size_t)ROWSd * BBd;  // [4,1024,1024] f32

    // ---- bump allocator over d_ws ----
    char* p = (char*)d_ws;
    auto alloc = [&](size_t bytes) { void* r = (void*)p; p += (bytes + 255) & ~(size_t)255; return r; };
    const size_t R = ROWSd;

    f16*  Qh   = (f16*)alloc(R * 1024 * 2);       // 8MB
    f16*  Kh   = (f16*)alloc(R * 1024 * 2);       // 8MB
    f16*  Vth  = (f16*)alloc(R * 1024 * 2);       // 8MB, [N][4096]
    f16*  Kch  = (f16*)alloc(R * 512 * 2);        // 4MB
    f16*  KSh  = (f16*)alloc(R * 512 * 2);        // 4MB
    f16*  QPh  = (f16*)alloc(R * 512 * 2);        // 4MB
    float* GATEf = (float*)alloc((size_t)Bd * Hd * Td * 4);
    ushort_t* CTXb = (ushort_t*)alloc(R * 1024 * 2); // 8MB
    float* LSOf  = (float*)alloc(R * 512 * 4);    // 8MB
    float* LPREf = (float*)alloc(R * 512 * 4);    // 8MB
    float* TPREf = (float*)alloc(R * 1024 * 4);   // 16MB
    ushort_t* XNb = (ushort_t*)alloc(R * 1024 * 2); // 8MB
    ushort_t* LPb = (ushort_t*)alloc(R * 512 * 2);  // 4MB
    ushort_t* TMb = (ushort_t*)alloc(R * 1024 * 2); // 8MB
    ushort_t* LTOb = (ushort_t*)alloc(R * 1024 * 2);// 8MB
    ushort_t* TLOb = (ushort_t*)alloc(R * 512 * 2); // 4MB
    ushort_t* LOb  = (ushort_t*)alloc(R * 512 * 2); // 4MB
    ushort_t* HBb  = (ushort_t*)alloc(R * 4096 * 2);// 32MB

    auto wt = [&](int K, int N) { return (ushort_t*)alloc((size_t)K * N * 2); };
    ushort_t* sa_q_t = wt(512, 512);  ushort_t* sa_k_t = wt(512, 512);  ushort_t* sa_v_t = wt(512, 512);
    ushort_t* sa_pk_t = wt(512, 512); ushort_t* sa_pq_t = wt(512, 512); ushort_t* sa_o_t = wt(512, 512);
    ushort_t* lt_q_t = wt(512, 1024); ushort_t* lt_k_t = wt(1024, 1024);
    ushort_t* lt_v_t = wt(1024, 1024); ushort_t* lt_o_t = wt(1024, 1024);
    ushort_t* tl_q_t = wt(1024, 512); ushort_t* tl_k_t = wt(512, 512);
    ushort_t* tl_v_t = wt(512, 512);  ushort_t* tl_o_t = wt(512, 512);
    ushort_t* ltp_t = wt(1024, 512);  ushort_t* tlp_t = wt(512, 1024);
    ushort_t* lf1_t = wt(512, 4096);  ushort_t* lf2_t = wt(4096, 512);
    ushort_t* tf1_t = wt(1024, 4096); ushort_t* tf2_t = wt(4096, 1024);

    const dim3 blk(256);

    auto tc = [&](const float* W, ushort_t* Wt, int K, int N) {
        tconv_kernel<<<dim3(N / 32, K / 32), blk, 0, stream>>>(W, Wt, K, N);
    };
    tc(sa_q_w, sa_q_t, 512, 512);   tc(sa_k_w, sa_k_t, 512, 512);   tc(sa_v_w, sa_v_t, 512, 512);
    tc(sa_pk_w, sa_pk_t, 512, 512); tc(sa_pq_w, sa_pq_t, 512, 512); tc(sa_o_w, sa_o_t, 512, 512);
    tc(lt_q_w, lt_q_t, 512, 1024);  tc(lt_k_w, lt_k_t, 1024, 1024);
    tc(lt_v_w, lt_v_t, 1024, 1024); tc(lt_o_w, lt_o_t, 1024, 1024);
    tc(tl_q_w, tl_q_t, 1024, 512);  tc(tl_k_w, tl_k_t, 512, 512);
    tc(tl_v_w, tl_v_t, 512, 512);   tc(tl_o_w, tl_o_t, 512, 512);
    tc(ltp_w, ltp_t, 1024, 512);    tc(tlp_w, tlp_t, 512, 1024);
    tc(lf1_w, lf1_t, 512, 4096);    tc(lf2_w, lf2_t, 4096, 512);
    tc(tf1_w, tf1_t, 1024, 4096);   tc(tf2_w, tf2_t, 4096, 1024);

    conv_kernel<<<dim3(R * 512 / 1024), blk, 0, stream>>>(layout_pos, LPb);
    conv_kernel<<<dim3(R * 1024 / 1024), blk, 0, stream>>>(text_memory, TMb);

#define G512(ACT, OM, RESM, Aa, Bb, bb, rr, cf, cb, ch, K) \
    mfma_gemm<2, 2, 1, 4, ACT, OM, RESM><<<dim3(512 / 128, ROWSd / 32), blk, 0, stream>>>(Aa, Bb, bb, rr, cf, cb, ch, ROWSd, 512, K)
#define G1024(ACT, OM, RESM, Aa, Bb, bb, rr, cf, cb, ch, K) \
    mfma_gemm<4, 2, 1, 4, ACT, OM, RESM><<<dim3(1024 / 128, ROWSd / 64), blk, 0, stream>>>(Aa, Bb, bb, rr, cf, cb, ch, ROWSd, 1024, K)
#define G4096(ACT, OM, RESM, Aa, Bb, bb, rr, cf, cb, ch, K) \
    mfma_gemm<4, 4, 2, 2, ACT, OM, RESM><<<dim3(4096 / 128, ROWSd / 128), blk, 0, stream>>>(Aa, Bb, bb, rr, cf, cb, ch, ROWSd, 4096, K)

    // ===== layout self-attention =====
    ln_kernel<512><<<dim3(ROWSd), blk, 0, stream>>>(layout_content, ln1_g, ln1_b, XNb);
    G512(0, 4, 0, XNb, sa_q_t, sa_q_b, nullptr, nullptr, nullptr, Qh, 512);
    G512(0, 4, 0, XNb, sa_k_t, sa_k_b, nullptr, nullptr, nullptr, Kch, 512);
    G512(0, 5, 0, XNb, sa_v_t, sa_v_b, nullptr, nullptr, nullptr, Vth, 512);
    G512(0, 4, 0, LPb, sa_pq_t, sa_pq_b, nullptr, nullptr, nullptr, QPh, 512);
    G512(0, 4, 2, LPb, sa_pk_t, sa_pk_b, Kch, nullptr, nullptr, KSh, 512);  // ksum = kp + kc
    gate_kernel<<<dim3(ROWSd), dim3(64), 0, stream>>>(Qh, sa_g_w, sa_g_b, GATEf);
    attn_mfma<64, true, true><<<dim3(Td / 64, Bd * Hd), blk, 0, stream>>>(
        Qh, QPh, KSh, Kch, Vth, GATEf, spatial_bias, CTXb, Td, Td, 0.125f);
    G512(0, 1, 1, CTXb, sa_o_t, sa_o_b, layout_content, LSOf, nullptr, nullptr, 512);

    // ===== layout -> text cross attention =====
    ln_kernel<512><<<dim3(ROWSd), blk, 0, stream>>>(LSOf, ln2_g, ln2_b, XNb);
    G1024(0, 4, 0, XNb, lt_q_t, lt_q_b, nullptr, nullptr, nullptr, Qh, 512);
    G1024(0, 4, 0, TMb, lt_k_t, lt_k_b, nullptr, nullptr, nullptr, Kh, 1024);
    G1024(0, 5, 0, TMb, lt_v_t, lt_v_b, nullptr, nullptr, nullptr, Vth, 1024);
    attn_mfma<128, false, false><<<dim3(Td / 64, Bd * Hd), blk, 0, stream>>>(
        Qh, nullptr, Kh, nullptr, Vth, nullptr, nullptr, CTXb, Td, Ld, 0.08838834764831845f);
    G1024(0, 2, 0, CTXb, lt_o_t, lt_o_b, nullptr, nullptr, LTOb, nullptr, 1024);
    G512(0, 1, 1, LTOb, ltp_t, ltp_b, LSOf, LPREf, nullptr, nullptr, 1024);

    // ===== layout FFN =====
    ln_kernel<512><<<dim3(ROWSd), blk, 0, stream>>>(LPREf, lfn_g, lfn_b, XNb);
    G4096(1, 2, 0, XNb, lf1_t, lf1_b, nullptr, nullptr, HBb, nullptr, 512);
    G512(0, 3, 1, HBb, lf2_t, lf2_b, LPREf, layout_out, LOb, nullptr, 4096);

    // ===== text -> layout cross attention =====
    ln_kernel<1024><<<dim3(ROWSd), blk, 0, stream>>>(text_x, tn1_g, tn1_b, XNb);
    G512(0, 4, 0, XNb, tl_q_t, tl_q_b, nullptr, nullptr, nullptr, Qh, 1024);
    G512(0, 4, 0, LOb, tl_k_t, tl_k_b, nullptr, nullptr, nullptr, Kh, 512);
    G512(0, 5, 0, LOb, tl_v_t, tl_v_b, nullptr, nullptr, nullptr, Vth, 512);
    attn_mfma<64, false, false><<<dim3(Td / 64, Bd * Hd), blk, 0, stream>>>(
        Qh, nullptr, Kh, nullptr, Vth, nullptr, nullptr, CTXb, Td, Td, 0.125f);
    G512(0, 2, 0, CTXb, tl_o_t, tl_o_b, nullptr, nullptr, TLOb, nullptr, 512);
    G1024(0, 1, 1, TLOb, tlp_t, tlp_b, text_x, TPREf, nullptr, nullptr, 512);

    // ===== text FFN =====
    ln_kernel<1024><<<dim3(ROWSd), blk, 0, stream>>>(TPREf, tfn_g, tfn_b, XNb);
    G4096(1, 2, 0, XNb, tf1_t, tf1_b, nullptr, nullptr, HBb, nullptr, 1024);
    G1024(0, 1, 1, HBb, tf2_t, tf2_b, TPREf, text_out, nullptr, nullptr, 4096);

#undef G512
#undef G1024
#undef G4096
}

// Round 5
// 1189.686 us; speedup vs baseline: 5.0703x; 1.0504x over previous
//
#include <hip/hip_runtime.h>

#define Bd 4
#define Td 1024
#define Ld 1024
#define HIDd 1024
#define BBd 512
#define FFd 4096
#define Hd 8
#define ROWSd 4096   // B*T = B*L

typedef unsigned short ushort_t;
typedef _Float16 f16;
typedef __attribute__((ext_vector_type(8))) short bf16x8;
typedef __attribute__((ext_vector_type(8))) _Float16 f16x8;
typedef __attribute__((ext_vector_type(4))) _Float16 f16x4;
typedef __attribute__((ext_vector_type(4))) float f32x4;

__device__ __forceinline__ float gelu_f(float x) {
    return 0.5f * x * (1.f + tanhf(0.7978845608028654f * (x + 0.044715f * x * x * x)));
}

__device__ __forceinline__ ushort_t f2b(float x) {
    union { float f; unsigned u; } v; v.f = x;
    unsigned r = v.u + 0x7fffu + ((v.u >> 16) & 1u);   // RTNE
    return (ushort_t)(r >> 16);
}

__device__ __forceinline__ void gload_lds16(const ushort_t* g, ushort_t* l) {
    __builtin_amdgcn_global_load_lds((__attribute__((address_space(1))) void*)(void*)g,
                                     (__attribute__((address_space(3))) void*)l,
                                     16, 0, 0);
}

// ---------------- LayerNorm: one block per row, bf16 out ----------------
template<int D>
__global__ __launch_bounds__(256) void ln_kernel(const float* __restrict__ x,
                                                 const float* __restrict__ g,
                                                 const float* __restrict__ b,
                                                 ushort_t* __restrict__ y)
{
    const int row = blockIdx.x;
    const int tid = threadIdx.x;
    const float* xr = x + (size_t)row * D;
    ushort_t* yr = y + (size_t)row * D;
    constexpr int PT = D / 256;
    float vals[PT];
    float s = 0.f, ss = 0.f;
#pragma unroll
    for (int i = 0; i < PT; i++) {
        float v = xr[tid + i * 256];
        vals[i] = v; s += v; ss += v * v;
    }
#pragma unroll
    for (int o = 32; o > 0; o >>= 1) { s += __shfl_down(s, o); ss += __shfl_down(ss, o); }
    __shared__ float rs[4], rss[4];
    const int wid = tid >> 6, lane = tid & 63;
    if (lane == 0) { rs[wid] = s; rss[wid] = ss; }
    __syncthreads();
    if (tid == 0) {
        float a = 0.f, c = 0.f;
        for (int i = 0; i < 4; i++) { a += rs[i]; c += rss[i]; }
        rs[0] = a; rss[0] = c;
    }
    __syncthreads();
    const float mean = rs[0] / D;
    const float var  = rss[0] / D - mean * mean;
    const float inv  = rsqrtf(fmaxf(var, 0.f) + 1e-6f);
#pragma unroll
    for (int i = 0; i < PT; i++) {
        const int idx = tid + i * 256;
        yr[idx] = f2b((vals[i] - mean) * inv * g[idx] + b[idx]);
    }
}

// ---------------- fp32 -> bf16 elementwise ----------------
__global__ __launch_bounds__(256) void conv_kernel(const float* __restrict__ x,
                                                   ushort_t* __restrict__ y)
{
    const int i = (blockIdx.x * 256 + threadIdx.x) * 4;
    const float4 v = *(const float4*)&x[i];
    y[i + 0] = f2b(v.x); y[i + 1] = f2b(v.y); y[i + 2] = f2b(v.z); y[i + 3] = f2b(v.w);
}

// ---------------- W[K,N] f32 -> Wt[N,K] bf16 ----------------
__global__ __launch_bounds__(256) void tconv_kernel(const float* __restrict__ W,
                                                    ushort_t* __restrict__ Wt,
                                                    int K, int N)
{
    __shared__ float tile[32][33];
    const int tid = threadIdx.x;
    const int tx = tid & 31, ty = tid >> 5;
    const int n0 = blockIdx.x * 32, k0 = blockIdx.y * 32;
#pragma unroll
    for (int i = 0; i < 32; i += 8)
        tile[ty + i][tx] = W[(size_t)(k0 + ty + i) * N + n0 + tx];
    __syncthreads();
#pragma unroll
    for (int i = 0; i < 32; i += 8) {
        const int n = n0 + ty + i, k = k0 + tx;
        Wt[(size_t)n * K + k] = f2b(tile[tx][ty + i]);
    }
}

// ---------------- bf16 MFMA GEMM: C[M,N] = A[M,K] @ Bt[N,K]^T + bias ----------------
// OMODE: 1=f32, 2=bf16, 3=f32+bf16, 4=f16, 5=f16 transposed [N][M]
// RESM:  0=none, 1=f32 residual, 2=f16 residual
template<int FM, int FN, int WR, int WC, int ACT, int OMODE, int RESM>
__global__ __launch_bounds__(256) void mfma_gemm(const ushort_t* __restrict__ A,
                                                 const ushort_t* __restrict__ Bt,
                                                 const float* __restrict__ bias,
                                                 const void* __restrict__ resv,
                                                 float* __restrict__ Cf,
                                                 ushort_t* __restrict__ Cb,
                                                 f16* __restrict__ Ch,
                                                 int M, int N, int K)
{
    constexpr int BM = WR * FM * 16, BN = WC * FN * 16, BK = 32;
    constexpr int ACH = BM / 16, BCH = BN / 16, TCH = ACH + BCH;
    constexpr int CPW = (TCH + 3) / 4;
    __shared__ alignas(16) ushort_t As[BM * BK];
    __shared__ alignas(16) ushort_t Bs[BN * BK];
    const int tid = threadIdx.x, w = tid >> 6, lane = tid & 63;
    const int wr = w / WC, wc = w % WC;
    const int m0 = blockIdx.y * BM, n0 = blockIdx.x * BN;
    const int lrow = lane >> 2, lkb = (lane & 3) * 8;
    const int fr = lane & 15, kg = (lane >> 4) * 8;

    f32x4 acc[FM][FN] = {};

    for (int k0 = 0; k0 < K; k0 += BK) {
        __syncthreads();
#pragma unroll
        for (int t = 0; t < CPW; t++) {
            const int c = w * CPW + t;
            if (c < ACH) {
                const int row = c * 16 + lrow;
                gload_lds16(A + (size_t)(m0 + row) * K + k0 + lkb, As + c * 512);
            } else if (c < TCH) {
                const int cc = c - ACH;
                const int row = cc * 16 + lrow;
                gload_lds16(Bt + (size_t)(n0 + row) * K + k0 + lkb, Bs + cc * 512);
            }
        }
        __syncthreads();
        bf16x8 af[FM], bfr[FN];
#pragma unroll
        for (int i = 0; i < FM; i++)
            af[i] = *(const bf16x8*)(As + (wr * FM * 16 + i * 16 + fr) * 32 + kg);
#pragma unroll
        for (int j = 0; j < FN; j++)
            bfr[j] = *(const bf16x8*)(Bs + (wc * FN * 16 + j * 16 + fr) * 32 + kg);
#pragma unroll
        for (int i = 0; i < FM; i++)
#pragma unroll
            for (int j = 0; j < FN; j++)
                acc[i][j] = __builtin_amdgcn_mfma_f32_16x16x32_bf16(af[i], bfr[j], acc[i][j], 0, 0, 0);
    }

    const int cr = (lane >> 4) * 4, ccol = lane & 15;
#pragma unroll
    for (int i = 0; i < FM; i++) {
#pragma unroll
        for (int j = 0; j < FN; j++) {
            const int n = n0 + wc * FN * 16 + j * 16 + ccol;
            const int mb = m0 + wr * FM * 16 + i * 16 + cr;
            float vv[4];
#pragma unroll
            for (int q = 0; q < 4; q++) {
                float v = acc[i][j][q] + bias[n];
                if (ACT == 1) v = gelu_f(v);
                if (RESM == 1) v += ((const float*)resv)[(size_t)(mb + q) * N + n];
                if (RESM == 2) v += (float)((const f16*)resv)[(size_t)(mb + q) * N + n];
                vv[q] = v;
            }
            if (OMODE == 1 || OMODE == 3) {
#pragma unroll
                for (int q = 0; q < 4; q++) Cf[(size_t)(mb + q) * N + n] = vv[q];
            }
            if (OMODE == 2 || OMODE == 3) {
#pragma unroll
                for (int q = 0; q < 4; q++) Cb[(size_t)(mb + q) * N + n] = f2b(vv[q]);
            }
            if (OMODE == 4) {
#pragma unroll
                for (int q = 0; q < 4; q++) Ch[(size_t)(mb + q) * N + n] = (f16)vv[q];
            }
            if (OMODE == 5) {
                f16x4 pk = { (f16)vv[0], (f16)vv[1], (f16)vv[2], (f16)vv[3] };
                *(f16x4*)&Ch[(size_t)n * M + mb] = pk;
            }
        }
    }
}

// ---------------- gate = sigmoid(qc . gw + gb) ----------------
__global__ __launch_bounds__(64) void gate_kernel(const f16* __restrict__ qc,
                                                  const float* __restrict__ gw,
                                                  const float* __restrict__ gb,
                                                  float* __restrict__ gate)
{
    const int bt = blockIdx.x;
    const int d = threadIdx.x;
    const float w = gw[d];
    const int b = bt >> 10, t = bt & 1023;
    const float gbv = gb[0];
#pragma unroll
    for (int h = 0; h < Hd; h++) {
        float v = (float)qc[(size_t)bt * BBd + h * 64 + d] * w;
#pragma unroll
        for (int o = 32; o > 0; o >>= 1) v += __shfl_xor(v, o);
        if (d == 0)
            gate[((size_t)b * Hd + h) * Td + t] = 1.f / (1.f + __expf(-(v + gbv)));
    }
}

// ---------------- MFMA flash attention, double-buffered staging ----------------
// Q,K fp16 [B*T][H*D]; Vt fp16 [H*D][B*Tk]; out bf16 [B*T][H*D].
// 4 waves x 16 q-rows. Tile t+1 global->reg loads issued at top of tile t;
// reg->LDS(buf^1) after PV; ONE barrier per tile. XCD-chunked block swizzle.
template<int D, int KT, bool CAUSAL, bool SA>
__global__ __launch_bounds__(256) void attn_mfma(const f16* __restrict__ Q,
                                                 const f16* __restrict__ Qp,
                                                 const f16* __restrict__ Km,
                                                 const f16* __restrict__ Kc,
                                                 const f16* __restrict__ Vt,
                                                 const float* __restrict__ gate,
                                                 const float* __restrict__ sb,
                                                 ushort_t* __restrict__ O,
                                                 int Tq, int Tk, float scale)
{
    constexpr int QB = 64, PAD = 8;
    constexpr int NS = D / 32;             // QK^T contraction slots
    constexpr int NDF = D / 16;            // output col fragments
    constexpr int KF = KT / 16;            // S col-fragments per tile
    constexpr int KROW = D + PAD;
    constexpr int VROW = KT + PAD;
    constexpr int NCH = KT * D / 2048;     // f16x8 chunks per thread (per operand)

    // XCD-chunked swizzle: consecutive work-ids (same bh) on the same XCD.
    const int gx = gridDim.x, nwg = gx * gridDim.y;
    const int flat = blockIdx.y * gx + blockIdx.x;
    const int cpx = nwg >> 3;                       // nwg % 8 == 0 holds for all our grids
    const int work = (flat & 7) * cpx + (flat >> 3);
    const int bh = work / gx, qblk = work % gx;
    const int b = bh >> 3, h = bh & 7;
    const int q0 = qblk * QB;
    const int tid = threadIdx.x, w = tid >> 6, lane = tid & 63;
    const int NH = Hd * D;
    const int qw0 = q0 + w * 16;
    const int fr = lane & 15;
    const int kg8 = (lane >> 4) * 8;
    const int cr4 = (lane >> 4) * 4;

    __shared__ alignas(16) f16 Ks[2][KT * KROW];
    __shared__ alignas(16) f16 Kcs[SA ? 2 : 1][SA ? KT * KROW : 8];
    __shared__ alignas(16) f16 Vts[2][D * VROW];
    __shared__ alignas(16) f16 Pw[4][16 * VROW];

    const size_t qb = ((size_t)b * Tq) * NH + (size_t)h * D;
    const size_t kb = ((size_t)b * Tk) * NH + (size_t)h * D;
    const size_t vtb = (size_t)h * D * ((size_t)Bd * Tk) + (size_t)b * Tk;

    // Q fragments from global (once per block)
    f16x8 aq[NS], ap[SA ? NS : 1];
#pragma unroll
    for (int s = 0; s < NS; s++) {
        aq[s] = *(const f16x8*)&Q[qb + (size_t)(qw0 + fr) * NH + s * 32 + kg8];
        if constexpr (SA)
            ap[s] = *(const f16x8*)&Qp[qb + (size_t)(qw0 + fr) * NH + s * 32 + kg8];
    }
    float gq[4];
    if constexpr (SA) {
#pragma unroll
        for (int r = 0; r < 4; r++)
            gq[r] = gate[(size_t)bh * Tq + qw0 + cr4 + r];
    }

    f16x8 krg[NCH], kcrg[SA ? NCH : 1], vrg[NCH];
    auto load_tile = [&](int k0) {
#pragma unroll
        for (int j = 0; j < NCH; j++) {
            const int i = tid + j * 256;
            const int row = i / (D / 8), c8 = (i % (D / 8)) * 8;
            krg[j] = *(const f16x8*)&Km[kb + (size_t)(k0 + row) * NH + c8];
            if constexpr (SA)
                kcrg[j] = *(const f16x8*)&Kc[kb + (size_t)(k0 + row) * NH + c8];
        }
#pragma unroll
        for (int j = 0; j < NCH; j++) {
            const int i = tid + j * 256;
            const int d = i / (KT / 8), c8 = (i % (KT / 8)) * 8;
            vrg[j] = *(const f16x8*)&Vt[vtb + (size_t)d * ((size_t)Bd * Tk) + k0 + c8];
        }
    };
    auto store_tile = [&](int buf) {
#pragma unroll
        for (int j = 0; j < NCH; j++) {
            const int i = tid + j * 256;
            const int row = i / (D / 8), c8 = (i % (D / 8)) * 8;
            *(f16x8*)&Ks[buf][row * KROW + c8] = krg[j];
            if constexpr (SA)
                *(f16x8*)&Kcs[buf][row * KROW + c8] = kcrg[j];
        }
#pragma unroll
        for (int j = 0; j < NCH; j++) {
            const int i = tid + j * 256;
            const int d = i / (KT / 8), c8 = (i % (KT / 8)) * 8;
            *(f16x8*)&Vts[buf][d * VROW + c8] = vrg[j];
        }
    };

    float m[4], l[4];
    f32x4 oacc[NDF] = {};
#pragma unroll
    for (int r = 0; r < 4; r++) { m[r] = -1e30f; l[r] = 0.f; }

    const int NT = CAUSAL ? (q0 / KT + 1) : (Tk / KT);

    load_tile(0);
    store_tile(0);
    __syncthreads();

    int cur = 0;
    for (int t = 0; t < NT; t++) {
        const int k0 = t * KT;
        const bool pf = (t + 1 < NT);
        if (pf) load_tile(k0 + KT);     // prefetch next tile into regs

        // ---- sb (gated spatial bias) prefetch for this tile ----
        float sbv[SA ? KF : 1][4];
        if constexpr (SA) {
#pragma unroll
            for (int kf = 0; kf < KF; kf++)
#pragma unroll
                for (int r = 0; r < 4; r++)
                    sbv[kf][r] = gq[r] *
                        sb[((size_t)bh * Tq + qw0 + cr4 + r) * Tk + k0 + kf * 16 + fr];
        }

        // ---- S fragments ----
        float pv[KF][4];
#pragma unroll
        for (int kf = 0; kf < KF; kf++) {
            f32x4 sacc = {};
#pragma unroll
            for (int s = 0; s < NS; s++) {
                const f16x8 bk = *(const f16x8*)&Ks[cur][(kf * 16 + fr) * KROW + s * 32 + kg8];
                sacc = __builtin_amdgcn_mfma_f32_16x16x32_f16(aq[s], bk, sacc, 0, 0, 0);
            }
            if constexpr (SA) {
#pragma unroll
                for (int s = 0; s < NS; s++) {
                    const f16x8 bkc = *(const f16x8*)&Kcs[cur][(kf * 16 + fr) * KROW + s * 32 + kg8];
                    sacc = __builtin_amdgcn_mfma_f32_16x16x32_f16(ap[s], bkc, sacc, 0, 0, 0);
                }
            }
            const int k = k0 + kf * 16 + fr;
#pragma unroll
            for (int r = 0; r < 4; r++) {
                const int q = qw0 + cr4 + r;
                float v = sacc[r] * scale;
                if constexpr (SA) v += sbv[kf][r];
                if (CAUSAL && k > q) v = -1e30f;
                pv[kf][r] = v;
            }
        }

        // ---- online softmax update ----
#pragma unroll
        for (int r = 0; r < 4; r++) {
            float mx = pv[0][r];
#pragma unroll
            for (int kf = 1; kf < KF; kf++) mx = fmaxf(mx, pv[kf][r]);
            mx = fmaxf(mx, __shfl_xor(mx, 1));
            mx = fmaxf(mx, __shfl_xor(mx, 2));
            mx = fmaxf(mx, __shfl_xor(mx, 4));
            mx = fmaxf(mx, __shfl_xor(mx, 8));
            const float mn = fmaxf(m[r], mx);
            const float fs = __expf(m[r] - mn);
            m[r] = mn;
            float ls = 0.f;
#pragma unroll
            for (int kf = 0; kf < KF; kf++) {
                const float p = __expf(pv[kf][r] - mn);
                pv[kf][r] = p; ls += p;
            }
            ls += __shfl_xor(ls, 1);
            ls += __shfl_xor(ls, 2);
            ls += __shfl_xor(ls, 4);
            ls += __shfl_xor(ls, 8);
            l[r] = l[r] * fs + ls;
#pragma unroll
            for (int df = 0; df < NDF; df++) oacc[df][r] *= fs;
        }

        // ---- P -> LDS (wave-private) ----
#pragma unroll
        for (int kf = 0; kf < KF; kf++)
#pragma unroll
            for (int r = 0; r < 4; r++)
                Pw[w][(cr4 + r) * VROW + kf * 16 + fr] = (f16)pv[kf][r];
        asm volatile("s_waitcnt lgkmcnt(0)" ::: "memory");
        __builtin_amdgcn_sched_barrier(0);

        // ---- PV ----
#pragma unroll
        for (int s = 0; s < KT / 32; s++) {
            const f16x8 pa = *(const f16x8*)&Pw[w][fr * VROW + s * 32 + kg8];
#pragma unroll
            for (int df = 0; df < NDF; df++) {
                const f16x8 vb = *(const f16x8*)&Vts[cur][(df * 16 + fr) * VROW + s * 32 + kg8];
                oacc[df] = __builtin_amdgcn_mfma_f32_16x16x32_f16(pa, vb, oacc[df], 0, 0, 0);
            }
        }

        // ---- write prefetched tile to the other buffer; single barrier ----
        if (pf) store_tile(cur ^ 1);
        __syncthreads();
        cur ^= 1;
    }

    // ---- epilogue ----
#pragma unroll
    for (int r = 0; r < 4; r++) {
        const float inv = 1.f / l[r];
        const size_t rowb = qb + (size_t)(qw0 + cr4 + r) * NH;
#pragma unroll
        for (int df = 0; df < NDF; df++)
            O[rowb + df * 16 + fr] = f2b(oacc[df][r] * inv);
    }
}

// ---------------------------------------------------------------
extern "C" void kernel_launch(void* const* d_in, const int* in_sizes, int n_in,
                              void* d_out, int out_size, void* d_ws, size_t ws_size,
                              hipStream_t stream)
{
    const float* layout_content = (const float*)d_in[0];
    const float* text_x         = (const float*)d_in[1];
    const float* text_memory    = (const float*)d_in[2];
    const float* spatial_bias   = (const float*)d_in[3];
    const float* layout_pos     = (const float*)d_in[4];
    // d_in[5] trg_mask (tril -> analytic), d_in[6] src_mask (all ones -> no-op)
    const float* sa_q_w = (const float*)d_in[7];   const float* sa_q_b = (const float*)d_in[8];
    const float* sa_k_w = (const float*)d_in[9];   const float* sa_k_b = (const float*)d_in[10];
    const float* sa_v_w = (const float*)d_in[11];  const float* sa_v_b = (const float*)d_in[12];
    const float* sa_pk_w = (const float*)d_in[13]; const float* sa_pk_b = (const float*)d_in[14];
    const float* sa_pq_w = (const float*)d_in[15]; const float* sa_pq_b = (const float*)d_in[16];
    const float* sa_o_w = (const float*)d_in[17];  const float* sa_o_b = (const float*)d_in[18];
    const float* lt_q_w = (const float*)d_in[19];  const float* lt_q_b = (const float*)d_in[20];
    const float* lt_k_w = (const float*)d_in[21];  const float* lt_k_b = (const float*)d_in[22];
    const float* lt_v_w = (const float*)d_in[23];  const float* lt_v_b = (const float*)d_in[24];
    const float* lt_o_w = (const float*)d_in[25];  const float* lt_o_b = (const float*)d_in[26];
    const float* tl_q_w = (const float*)d_in[27];  const float* tl_q_b = (const float*)d_in[28];
    const float* tl_k_w = (const float*)d_in[29];  const float* tl_k_b = (const float*)d_in[30];
    const float* tl_v_w = (const float*)d_in[31];  const float* tl_v_b = (const float*)d_in[32];
    const float* tl_o_w = (const float*)d_in[33];  const float* tl_o_b = (const float*)d_in[34];
    const float* ltp_w = (const float*)d_in[35];   const float* ltp_b = (const float*)d_in[36];
    const float* tlp_w = (const float*)d_in[37];   const float* tlp_b = (const float*)d_in[38];
    const float* lf1_w = (const float*)d_in[39];   const float* lf1_b = (const float*)d_in[40];
    const float* lf2_w = (const float*)d_in[41];   const float* lf2_b = (const float*)d_in[42];
    const float* tf1_w = (const float*)d_in[43];   const float* tf1_b = (const float*)d_in[44];
    const float* tf2_w = (const float*)d_in[45];   const float* tf2_b = (const float*)d_in[46];
    const float* sa_g_w = (const float*)d_in[47];  const float* sa_g_b = (const float*)d_in[48];
    const float* ln1_g = (const float*)d_in[49];   const float* ln1_b = (const float*)d_in[50];
    const float* ln2_g = (const float*)d_in[51];   const float* ln2_b = (const float*)d_in[52];
    const float* tn1_g = (const float*)d_in[53];   const float* tn1_b = (const float*)d_in[54];
    const float* lfn_g = (const float*)d_in[55];   const float* lfn_b = (const float*)d_in[56];
    const float* tfn_g = (const float*)d_in[57];   const float* tfn_b = (const float*)d_in[58];

    float* out = (float*)d_out;
    float* layout_out = out;                        // [4,1024,512] f32
    float* text_out   = out + (size_t)ROWSd * BBd;  // [4,1024,1024] f32

    // ---- bump allocator over d_ws ----
    char* p = (char*)d_ws;
    auto alloc = [&](size_t bytes) { void* r = (void*)p; p += (bytes + 255) & ~(size_t)255; return r; };
    const size_t R = ROWSd;

    f16*  Qh   = (f16*)alloc(R * 1024 * 2);       // 8MB
    f16*  Kh   = (f16*)alloc(R * 1024 * 2);       // 8MB
    f16*  Vth  = (f16*)alloc(R * 1024 * 2);       // 8MB, [N][4096]
    f16*  Kch  = (f16*)alloc(R * 512 * 2);        // 4MB
    f16*  KSh  = (f16*)alloc(R * 512 * 2);        // 4MB
    f16*  QPh  = (f16*)alloc(R * 512 * 2);        // 4MB
    float* GATEf = (float*)alloc((size_t)Bd * Hd * Td * 4);
    ushort_t* CTXb = (ushort_t*)alloc(R * 1024 * 2); // 8MB
    float* LSOf  = (float*)alloc(R * 512 * 4);    // 8MB
    float* LPREf = (float*)alloc(R * 512 * 4);    // 8MB
    float* TPREf = (float*)alloc(R * 1024 * 4);   // 16MB
    ushort_t* XNb = (ushort_t*)alloc(R * 1024 * 2); // 8MB
    ushort_t* LPb = (ushort_t*)alloc(R * 512 * 2);  // 4MB
    ushort_t* TMb = (ushort_t*)alloc(R * 1024 * 2); // 8MB
    ushort_t* LTOb = (ushort_t*)alloc(R * 1024 * 2);// 8MB
    ushort_t* TLOb = (ushort_t*)alloc(R * 512 * 2); // 4MB
    ushort_t* LOb  = (ushort_t*)alloc(R * 512 * 2); // 4MB
    ushort_t* HBb  = (ushort_t*)alloc(R * 4096 * 2);// 32MB

    auto wt = [&](int K, int N) { return (ushort_t*)alloc((size_t)K * N * 2); };
    ushort_t* sa_q_t = wt(512, 512);  ushort_t* sa_k_t = wt(512, 512);  ushort_t* sa_v_t = wt(512, 512);
    ushort_t* sa_pk_t = wt(512, 512); ushort_t* sa_pq_t = wt(512, 512); ushort_t* sa_o_t = wt(512, 512);
    ushort_t* lt_q_t = wt(512, 1024); ushort_t* lt_k_t = wt(1024, 1024);
    ushort_t* lt_v_t = wt(1024, 1024); ushort_t* lt_o_t = wt(1024, 1024);
    ushort_t* tl_q_t = wt(1024, 512); ushort_t* tl_k_t = wt(512, 512);
    ushort_t* tl_v_t = wt(512, 512);  ushort_t* tl_o_t = wt(512, 512);
    ushort_t* ltp_t = wt(1024, 512);  ushort_t* tlp_t = wt(512, 1024);
    ushort_t* lf1_t = wt(512, 4096);  ushort_t* lf2_t = wt(4096, 512);
    ushort_t* tf1_t = wt(1024, 4096); ushort_t* tf2_t = wt(4096, 1024);

    const dim3 blk(256);

    auto tc = [&](const float* W, ushort_t* Wt, int K, int N) {
        tconv_kernel<<<dim3(N / 32, K / 32), blk, 0, stream>>>(W, Wt, K, N);
    };
    tc(sa_q_w, sa_q_t, 512, 512);   tc(sa_k_w, sa_k_t, 512, 512);   tc(sa_v_w, sa_v_t, 512, 512);
    tc(sa_pk_w, sa_pk_t, 512, 512); tc(sa_pq_w, sa_pq_t, 512, 512); tc(sa_o_w, sa_o_t, 512, 512);
    tc(lt_q_w, lt_q_t, 512, 1024);  tc(lt_k_w, lt_k_t, 1024, 1024);
    tc(lt_v_w, lt_v_t, 1024, 1024); tc(lt_o_w, lt_o_t, 1024, 1024);
    tc(tl_q_w, tl_q_t, 1024, 512);  tc(tl_k_w, tl_k_t, 512, 512);
    tc(tl_v_w, tl_v_t, 512, 512);   tc(tl_o_w, tl_o_t, 512, 512);
    tc(ltp_w, ltp_t, 1024, 512);    tc(tlp_w, tlp_t, 512, 1024);
    tc(lf1_w, lf1_t, 512, 4096);    tc(lf2_w, lf2_t, 4096, 512);
    tc(tf1_w, tf1_t, 1024, 4096);   tc(tf2_w, tf2_t, 4096, 1024);

    conv_kernel<<<dim3(R * 512 / 1024), blk, 0, stream>>>(layout_pos, LPb);
    conv_kernel<<<dim3(R * 1024 / 1024), blk, 0, stream>>>(text_memory, TMb);

    // GEMM launchers:
    //  G512   : 32x128 tile, 512 blocks (short-K, N=512)
    //  G1024  : 64x128 tile, 512 blocks (short-K, N=1024)
    //  G12864 : 128x64 tile, 256 blocks (long-K into N=512)
    //  G128SQ : 128x128 m97 tile (long-K, N>=1024)
#define G512(ACT, OM, RESM, Aa, Bb, bb, rr, cf, cb, ch, K) \
    mfma_gemm<2, 2, 1, 4, ACT, OM, RESM><<<dim3(512 / 128, ROWSd / 32), blk, 0, stream>>>(Aa, Bb, bb, rr, cf, cb, ch, ROWSd, 512, K)
#define G1024(ACT, OM, RESM, Aa, Bb, bb, rr, cf, cb, ch, K) \
    mfma_gemm<4, 2, 1, 4, ACT, OM, RESM><<<dim3(1024 / 128, ROWSd / 64), blk, 0, stream>>>(Aa, Bb, bb, rr, cf, cb, ch, ROWSd, 1024, K)
#define G12864(ACT, OM, RESM, Aa, Bb, bb, rr, cf, cb, ch, K) \
    mfma_gemm<4, 2, 2, 2, ACT, OM, RESM><<<dim3(512 / 64, ROWSd / 128), blk, 0, stream>>>(Aa, Bb, bb, rr, cf, cb, ch, ROWSd, 512, K)
#define G128SQ(ACT, OM, RESM, Aa, Bb, bb, rr, cf, cb, ch, N, K) \
    mfma_gemm<4, 4, 2, 2, ACT, OM, RESM><<<dim3((N) / 128, ROWSd / 128), blk, 0, stream>>>(Aa, Bb, bb, rr, cf, cb, ch, ROWSd, N, K)

    // ===== layout self-attention =====
    ln_kernel<512><<<dim3(ROWSd), blk, 0, stream>>>(layout_content, ln1_g, ln1_b, XNb);
    G512(0, 4, 0, XNb, sa_q_t, sa_q_b, nullptr, nullptr, nullptr, Qh, 512);
    G512(0, 4, 0, XNb, sa_k_t, sa_k_b, nullptr, nullptr, nullptr, Kch, 512);
    G512(0, 5, 0, XNb, sa_v_t, sa_v_b, nullptr, nullptr, nullptr, Vth, 512);
    G512(0, 4, 0, LPb, sa_pq_t, sa_pq_b, nullptr, nullptr, nullptr, QPh, 512);
    G512(0, 4, 2, LPb, sa_pk_t, sa_pk_b, Kch, nullptr, nullptr, KSh, 512);  // ksum = kp + kc
    gate_kernel<<<dim3(ROWSd), dim3(64), 0, stream>>>(Qh, sa_g_w, sa_g_b, GATEf);
    attn_mfma<64, 64, true, true><<<dim3(Td / 64, Bd * Hd), blk, 0, stream>>>(
        Qh, QPh, KSh, Kch, Vth, GATEf, spatial_bias, CTXb, Td, Td, 0.125f);
    G512(0, 1, 1, CTXb, sa_o_t, sa_o_b, layout_content, LSOf, nullptr, nullptr, 512);

    // ===== layout -> text cross attention =====
    ln_kernel<512><<<dim3(ROWSd), blk, 0, stream>>>(LSOf, ln2_g, ln2_b, XNb);
    G1024(0, 4, 0, XNb, lt_q_t, lt_q_b, nullptr, nullptr, nullptr, Qh, 512);
    G128SQ(0, 4, 0, TMb, lt_k_t, lt_k_b, nullptr, nullptr, nullptr, Kh, 1024, 1024);
    G128SQ(0, 5, 0, TMb, lt_v_t, lt_v_b, nullptr, nullptr, nullptr, Vth, 1024, 1024);
    attn_mfma<128, 32, false, false><<<dim3(Td / 64, Bd * Hd), blk, 0, stream>>>(
        Qh, nullptr, Kh, nullptr, Vth, nullptr, nullptr, CTXb, Td, Ld, 0.08838834764831845f);
    G128SQ(0, 2, 0, CTXb, lt_o_t, lt_o_b, nullptr, nullptr, LTOb, nullptr, 1024, 1024);
    G12864(0, 1, 1, LTOb, ltp_t, ltp_b, LSOf, LPREf, nullptr, nullptr, 1024);

    // ===== layout FFN =====
    ln_kernel<512><<<dim3(ROWSd), blk, 0, stream>>>(LPREf, lfn_g, lfn_b, XNb);
    G128SQ(1, 2, 0, XNb, lf1_t, lf1_b, nullptr, nullptr, HBb, nullptr, 4096, 512);
    G12864(0, 3, 1, HBb, lf2_t, lf2_b, LPREf, layout_out, LOb, nullptr, 4096);

    // ===== text -> layout cross attention =====
    ln_kernel<1024><<<dim3(ROWSd), blk, 0, stream>>>(text_x, tn1_g, tn1_b, XNb);
    G12864(0, 4, 0, XNb, tl_q_t, tl_q_b, nullptr, nullptr, nullptr, Qh, 1024);
    G512(0, 4, 0, LOb, tl_k_t, tl_k_b, nullptr, nullptr, nullptr, Kh, 512);
    G512(0, 5, 0, LOb, tl_v_t, tl_v_b, nullptr, nullptr, nullptr, Vth, 512);
    attn_mfma<64, 64, false, false><<<dim3(Td / 64, Bd * Hd), blk, 0, stream>>>(
        Qh, nullptr, Kh, nullptr, Vth, nullptr, nullptr, CTXb, Td, Td, 0.125f);
    G512(0, 2, 0, CTXb, tl_o_t, tl_o_b, nullptr, nullptr, TLOb, nullptr, 512);
    G1024(0, 1, 1, TLOb, tlp_t, tlp_b, text_x, TPREf, nullptr, nullptr, 512);

    // ===== text FFN =====
    ln_kernel<1024><<<dim3(ROWSd), blk, 0, stream>>>(TPREf, tfn_g, tfn_b, XNb);
    G128SQ(1, 2, 0, XNb, tf1_t, tf1_b, nullptr, nullptr, HBb, nullptr, 4096, 1024);
    G128SQ(0, 1, 1, HBb, tf2_t, tf2_b, TPREf, text_out, nullptr, nullptr, 1024, 4096);

#undef G512
#undef G1024
#undef G12864
#undef G128SQ
}